// Round 1
// baseline (1548.159 us; speedup 1.0000x reference)
//
#include <hip/hip_runtime.h>
#include <hip/hip_bf16.h>
#include <math.h>

#define BB 128
#define NN2 1024
#define NN3 256
#define NN4 64
#define DD 128
#define HH 2
#define DH 64
#define MLPD 512
#define EPSF 1e-5f

using bf16 = __hip_bfloat16;

__device__ inline float wave_sum64(float v) {
#pragma unroll
    for (int m = 32; m >= 1; m >>= 1) v += __shfl_xor(v, m, 64);
    return v;
}
__device__ inline float wave_max64(float v) {
#pragma unroll
    for (int m = 32; m >= 1; m >>= 1) v = fmaxf(v, __shfl_xor(v, m, 64));
    return v;
}

// ---------------- kv path: LN + (k,v) projection + channel softmax on k ----
__global__ __launch_bounds__(256) void kv_kernel(
    const float* __restrict__ in, const float* __restrict__ pe,
    const float* __restrict__ lnw, const float* __restrict__ lnb,
    const float* __restrict__ kw, const float* __restrict__ kb,
    const float* __restrict__ vw, const float* __restrict__ vb,
    float* __restrict__ ks, float* __restrict__ vs, int Ntok)
{
    __shared__ float kin[4][DD];
    __shared__ float vin[4][DD];
    int wave = threadIdx.x >> 6;
    int lane = threadIdx.x & 63;
    int row = blockIdx.x * 4 + wave;
    int tok = row % Ntok;
    const float* xr = in + (size_t)row * DD;
    float x0 = xr[lane], x1 = xr[lane + 64];
    float s = wave_sum64(x0 + x1);
    float mean = s * (1.0f / DD);
    float d0 = x0 - mean, d1 = x1 - mean;
    float s2 = wave_sum64(d0 * d0 + d1 * d1);
    float rstd = rsqrtf(s2 * (1.0f / DD) + EPSF);
    float n0 = d0 * rstd * lnw[lane] + lnb[lane];
    float n1 = d1 * rstd * lnw[lane + 64] + lnb[lane + 64];
    kin[wave][lane]      = n0 + pe[tok * DD + lane];
    kin[wave][lane + 64] = n1 + pe[tok * DD + lane + 64];
    vin[wave][lane]      = n0;
    vin[wave][lane + 64] = n1;
    __syncthreads();
    float ak0 = 0.f, ak1 = 0.f, av0 = 0.f, av1 = 0.f;
    for (int k = 0; k < DD; ++k) {
        float kk = kin[wave][k], vv = vin[wave][k];
        ak0 += kk * kw[k * DD + lane];
        ak1 += kk * kw[k * DD + lane + 64];
        av0 += vv * vw[k * DD + lane];
        av1 += vv * vw[k * DD + lane + 64];
    }
    ak0 += kb[lane]; ak1 += kb[lane + 64];
    av0 += vb[lane]; av1 += vb[lane + 64];
    // channel softmax per head (64 channels == 64 lanes)
    float m0 = wave_max64(ak0);
    float m1 = wave_max64(ak1);
    float e0 = expf(ak0 - m0), e1 = expf(ak1 - m1);
    float z0 = wave_sum64(e0), z1 = wave_sum64(e1);
    float* ksr = ks + (size_t)row * DD;
    float* vsr = vs + (size_t)row * DD;
    ksr[lane]      = e0 / z0;
    ksr[lane + 64] = e1 / z1;
    vsr[lane]      = av0;
    vsr[lane + 64] = av1;
}

// ---------------- ctx[b,h,d,e] = sum_n ks[b,n,h,d]*vs[b,n,h,e] -------------
__global__ __launch_bounds__(256) void ctx_kernel(
    const float* __restrict__ ks, const float* __restrict__ vs,
    float* __restrict__ ctx, int Nk)
{
    __shared__ float kst[8][DH];
    __shared__ float vst[8][DH];
    int b = blockIdx.x >> 1, h = blockIdx.x & 1;
    int t = threadIdx.x;
    int e = t & 63, dg = t >> 6;
    float acc[16];
#pragma unroll
    for (int i = 0; i < 16; ++i) acc[i] = 0.f;
    for (int n0 = 0; n0 < Nk; n0 += 8) {
#pragma unroll
        for (int i = 0; i < 4; ++i) {
            int flat = i * 256 + t;        // 0..1023
            int tokn = flat >> 7;
            int which = (flat >> 6) & 1;
            int ch = flat & 63;
            size_t g = ((size_t)(b * Nk + n0 + tokn)) * DD + h * DH + ch;
            if (which == 0) kst[tokn][ch] = ks[g];
            else            vst[tokn][ch] = vs[g];
        }
        __syncthreads();
#pragma unroll
        for (int tk = 0; tk < 8; ++tk) {
            float vv = vst[tk][e];
#pragma unroll
            for (int i = 0; i < 16; ++i)
                acc[i] += kst[tk][dg * 16 + i] * vv;
        }
        __syncthreads();
    }
    float* cp = ctx + ((size_t)(b * HH + h)) * DH * DH;
#pragma unroll
    for (int i = 0; i < 16; ++i)
        cp[(dg * 16 + i) * DH + e] = acc[i];
}

// ---------------- q projections: LN(f2)+pe2 -> q1,q2 (bf16) ----------------
__global__ __launch_bounds__(256) void qproj_kernel(
    const float* __restrict__ f2, const float* __restrict__ pe2,
    const float* __restrict__ lnw, const float* __restrict__ lnb,
    const float* __restrict__ q1w, const float* __restrict__ q1b,
    const float* __restrict__ q2w, const float* __restrict__ q2b,
    bf16* __restrict__ q1o, bf16* __restrict__ q2o)
{
    __shared__ float qin[8][DD];
    int t = threadIdx.x;
    int base = blockIdx.x * 8;
    {
        int r = t >> 5, l = t & 31;
        int row = base + r;
        int tok = row & (NN2 - 1);
        const float* xr = f2 + (size_t)row * DD;
        float x[4];
#pragma unroll
        for (int j = 0; j < 4; ++j) x[j] = xr[l + 32 * j];
        float s = x[0] + x[1] + x[2] + x[3];
#pragma unroll
        for (int m = 16; m >= 1; m >>= 1) s += __shfl_xor(s, m, 32);
        float mean = s * (1.0f / DD);
        float vsum = 0.f;
#pragma unroll
        for (int j = 0; j < 4; ++j) { float d = x[j] - mean; vsum += d * d; }
#pragma unroll
        for (int m = 16; m >= 1; m >>= 1) vsum += __shfl_xor(vsum, m, 32);
        float rstd = rsqrtf(vsum * (1.0f / DD) + EPSF);
#pragma unroll
        for (int j = 0; j < 4; ++j) {
            int c = l + 32 * j;
            qin[r][c] = (x[j] - mean) * rstd * lnw[c] + lnb[c] + pe2[tok * DD + c];
        }
    }
    __syncthreads();
    int c = t & 127;
    int sel = t >> 7;
    const float* w = sel ? q2w : q1w;
    float acc[8];
#pragma unroll
    for (int r = 0; r < 8; ++r) acc[r] = 0.f;
    for (int k = 0; k < DD; ++k) {
        float wv = w[k * DD + c];
#pragma unroll
        for (int r = 0; r < 8; ++r) acc[r] += qin[r][k] * wv;
    }
    float bias = sel ? q2b[c] : q1b[c];
    bf16* outp = sel ? q2o : q1o;
#pragma unroll
    for (int r = 0; r < 8; ++r)
        outp[(size_t)(base + r) * DD + c] = __float2bfloat16(acc[r] + bias);
}

// ---------------- token-axis softmax stats (online max/sum) ----------------
__global__ __launch_bounds__(256) void qstats_kernel(
    const bf16* __restrict__ q1, const bf16* __restrict__ q2,
    float* __restrict__ stats)
{
    __shared__ float red[4][256];
    int b = blockIdx.x;
    int t = threadIdx.x;
    int c = t & 127, half = t >> 7;
    float m1 = -1e30f, s1 = 0.f, m2 = -1e30f, s2 = 0.f;
    for (int n = half; n < NN2; n += 2) {
        size_t g = ((size_t)(b * NN2 + n)) * DD + c;
        float v1 = __bfloat162float(q1[g]);
        float v2 = __bfloat162float(q2[g]);
        float nm1 = fmaxf(m1, v1);
        s1 = s1 * expf(m1 - nm1) + expf(v1 - nm1);
        m1 = nm1;
        float nm2 = fmaxf(m2, v2);
        s2 = s2 * expf(m2 - nm2) + expf(v2 - nm2);
        m2 = nm2;
    }
    red[0][t] = m1; red[1][t] = s1; red[2][t] = m2; red[3][t] = s2;
    __syncthreads();
    if (half == 0) {
        float om1 = red[0][c + 128], os1 = red[1][c + 128];
        float om2 = red[2][c + 128], os2 = red[3][c + 128];
        float M1 = fmaxf(m1, om1);
        float S1 = s1 * expf(m1 - M1) + os1 * expf(om1 - M1);
        float M2 = fmaxf(m2, om2);
        float S2 = s2 * expf(m2 - M2) + os2 * expf(om2 - M2);
        int idx = b * DD + c;
        stats[idx]               = M1;
        stats[16384 + idx]       = 1.0f / S1;
        stats[2 * 16384 + idx]   = M2;
        stats[3 * 16384 + idx]   = 1.0f / S2;
    }
}

// ---------------- attention: qs -> ctx matvec -> rp proj -> x = f2+attn ----
__global__ __launch_bounds__(256) void attn_kernel(
    const bf16* __restrict__ q1, const bf16* __restrict__ q2,
    const float* __restrict__ stats,
    const float* __restrict__ ctx1, const float* __restrict__ ctx2,
    const float* __restrict__ rpw, const float* __restrict__ rpb,
    const float* __restrict__ f2, float* __restrict__ x)
{
    __shared__ float qs[16][256];
    __shared__ float cat[16][256];
    int t = threadIdx.x;
    int base = blockIdx.x * 16;
    int b = base >> 10;
    {
        int sel = t >> 7, c = t & 127;
        const bf16* qp = sel ? q2 : q1;
        float m  = stats[sel * 2 * 16384 + b * DD + c];
        float rs = stats[sel * 2 * 16384 + 16384 + b * DD + c];
#pragma unroll
        for (int r = 0; r < 16; ++r) {
            float qv = __bfloat162float(qp[(size_t)(base + r) * DD + c]);
            qs[r][t] = expf(qv - m) * rs;
        }
    }
    __syncthreads();
    {
        int sel = t >> 7, c = t & 127;
        int h = c >> 6, e = c & 63;
        const float* cp = (sel ? ctx2 : ctx1) + ((size_t)(b * HH + h)) * DH * DH + e;
        int qoff = sel * 128 + h * 64;
        float acc[16];
#pragma unroll
        for (int r = 0; r < 16; ++r) acc[r] = 0.f;
        for (int d = 0; d < DH; ++d) {
            float cv = cp[d * DH];
#pragma unroll
            for (int r = 0; r < 16; ++r) acc[r] += cv * qs[r][qoff + d];
        }
#pragma unroll
        for (int r = 0; r < 16; ++r) cat[r][t] = acc[r];
    }
    __syncthreads();
    {
        int outc = t & 127, rg = t >> 7;
        float acc[8];
#pragma unroll
        for (int r = 0; r < 8; ++r) acc[r] = 0.f;
        for (int j = 0; j < 2 * DD; ++j) {
            float wv = rpw[j * DD + outc];
#pragma unroll
            for (int r = 0; r < 8; ++r) acc[r] += cat[rg * 8 + r][j] * wv;
        }
#pragma unroll
        for (int r = 0; r < 8; ++r) {
            size_t g = (size_t)(base + rg * 8 + r) * DD + outc;
            x[g] = f2[g] + acc[r] + rpb[outc];
        }
    }
}

// ---------------- LN(x) -> MLP(gelu) -> out = x + h -----------------------
__global__ __launch_bounds__(256) void mlp_kernel(
    const float* __restrict__ x,
    const float* __restrict__ lnw, const float* __restrict__ lnb,
    const float* __restrict__ ff1w, const float* __restrict__ ff1b,
    const float* __restrict__ ff2w, const float* __restrict__ ff2b,
    float* __restrict__ out)
{
    __shared__ float xres[16][DD];
    __shared__ float xn[16][DD];
    __shared__ float hid[16][MLPD];
    int t = threadIdx.x;
    int base = blockIdx.x * 16;
    {
        int r = t >> 4, l = t & 15;
        const float* xr = x + (size_t)(base + r) * DD;
        float v[8];
#pragma unroll
        for (int j = 0; j < 8; ++j) v[j] = xr[l + 16 * j];
        float s = 0.f;
#pragma unroll
        for (int j = 0; j < 8; ++j) s += v[j];
#pragma unroll
        for (int m = 8; m >= 1; m >>= 1) s += __shfl_xor(s, m, 16);
        float mean = s * (1.0f / DD);
        float vs = 0.f;
#pragma unroll
        for (int j = 0; j < 8; ++j) { float d = v[j] - mean; vs += d * d; }
#pragma unroll
        for (int m = 8; m >= 1; m >>= 1) vs += __shfl_xor(vs, m, 16);
        float rstd = rsqrtf(vs * (1.0f / DD) + EPSF);
#pragma unroll
        for (int j = 0; j < 8; ++j) {
            int c = l + 16 * j;
            xres[r][c] = v[j];
            xn[r][c] = (v[j] - mean) * rstd * lnw[c] + lnb[c];
        }
    }
    __syncthreads();
    {
        int j0 = t, j1 = t + 256;
        float a0[16], a1[16];
#pragma unroll
        for (int r = 0; r < 16; ++r) { a0[r] = 0.f; a1[r] = 0.f; }
        for (int k = 0; k < DD; ++k) {
            float w0 = ff1w[k * MLPD + j0];
            float w1 = ff1w[k * MLPD + j1];
#pragma unroll
            for (int r = 0; r < 16; ++r) {
                float xv = xn[r][k];
                a0[r] += xv * w0;
                a1[r] += xv * w1;
            }
        }
        float b0 = ff1b[j0], b1 = ff1b[j1];
#pragma unroll
        for (int r = 0; r < 16; ++r) {
            float h0 = a0[r] + b0, h1 = a1[r] + b1;
            hid[r][j0] = 0.5f * h0 * (1.0f + erff(h0 * 0.70710678118654752f));
            hid[r][j1] = 0.5f * h1 * (1.0f + erff(h1 * 0.70710678118654752f));
        }
    }
    __syncthreads();
    {
        int outc = t & 127, rg = t >> 7;
        float acc[8];
#pragma unroll
        for (int r = 0; r < 8; ++r) acc[r] = 0.f;
        for (int j = 0; j < MLPD; ++j) {
            float wv = ff2w[j * DD + outc];
#pragma unroll
            for (int r = 0; r < 8; ++r) acc[r] += hid[rg * 8 + r][j] * wv;
        }
#pragma unroll
        for (int r = 0; r < 8; ++r) {
            size_t g = (size_t)(base + rg * 8 + r) * DD + outc;
            out[g] = xres[rg * 8 + r][outc] + acc[r] + ff2b[outc];
        }
    }
}

extern "C" void kernel_launch(void* const* d_in, const int* in_sizes, int n_in,
                              void* d_out, int out_size, void* d_ws, size_t ws_size,
                              hipStream_t stream) {
    const float* f2   = (const float*)d_in[0];
    const float* f3   = (const float*)d_in[1];
    const float* f4   = (const float*)d_in[2];
    const float* pe2  = (const float*)d_in[3];
    const float* pe3  = (const float*)d_in[4];
    const float* pe4  = (const float*)d_in[5];
    const float* ln1w = (const float*)d_in[6];
    const float* ln1b = (const float*)d_in[7];
    const float* ln2w = (const float*)d_in[8];
    const float* ln2b = (const float*)d_in[9];
    const float* ln3w = (const float*)d_in[10];
    const float* ln3b = (const float*)d_in[11];
    const float* ln4w = (const float*)d_in[12];
    const float* ln4b = (const float*)d_in[13];
    const float* q1w  = (const float*)d_in[14];
    const float* q1b  = (const float*)d_in[15];
    const float* k1w  = (const float*)d_in[16];
    const float* k1b  = (const float*)d_in[17];
    const float* v1w  = (const float*)d_in[18];
    const float* v1b  = (const float*)d_in[19];
    const float* q2w  = (const float*)d_in[20];
    const float* q2b  = (const float*)d_in[21];
    const float* k2w  = (const float*)d_in[22];
    const float* k2b  = (const float*)d_in[23];
    const float* v2w  = (const float*)d_in[24];
    const float* v2b  = (const float*)d_in[25];
    const float* rpw  = (const float*)d_in[26];
    const float* rpb  = (const float*)d_in[27];
    const float* ff1w = (const float*)d_in[28];
    const float* ff1b = (const float*)d_in[29];
    const float* ff2w = (const float*)d_in[30];
    const float* ff2b = (const float*)d_in[31];

    char* ws = (char*)d_ws;
    size_t off = 0;
    bf16* q1 = (bf16*)(ws + off);  off += (size_t)BB * NN2 * DD * sizeof(bf16);
    bf16* q2 = (bf16*)(ws + off);  off += (size_t)BB * NN2 * DD * sizeof(bf16);
    float* ks3 = (float*)(ws + off); off += (size_t)BB * NN3 * DD * sizeof(float);
    float* vs3 = (float*)(ws + off); off += (size_t)BB * NN3 * DD * sizeof(float);
    float* ks4 = (float*)(ws + off); off += (size_t)BB * NN4 * DD * sizeof(float);
    float* vs4 = (float*)(ws + off); off += (size_t)BB * NN4 * DD * sizeof(float);
    float* ctx1 = (float*)(ws + off); off += (size_t)BB * HH * DH * DH * sizeof(float);
    float* ctx2 = (float*)(ws + off); off += (size_t)BB * HH * DH * DH * sizeof(float);
    float* stats = (float*)(ws + off); off += (size_t)4 * BB * DD * sizeof(float);
    float* xbuf = (float*)(ws + off); off += (size_t)BB * NN2 * DD * sizeof(float);

    kv_kernel<<<BB * NN3 / 4, 256, 0, stream>>>(f3, pe3, ln2w, ln2b, k1w, k1b, v1w, v1b, ks3, vs3, NN3);
    kv_kernel<<<BB * NN4 / 4, 256, 0, stream>>>(f4, pe4, ln3w, ln3b, k2w, k2b, v2w, v2b, ks4, vs4, NN4);
    ctx_kernel<<<BB * HH, 256, 0, stream>>>(ks3, vs3, ctx1, NN3);
    ctx_kernel<<<BB * HH, 256, 0, stream>>>(ks4, vs4, ctx2, NN4);
    qproj_kernel<<<BB * NN2 / 8, 256, 0, stream>>>(f2, pe2, ln1w, ln1b, q1w, q1b, q2w, q2b, q1, q2);
    qstats_kernel<<<BB, 256, 0, stream>>>(q1, q2, stats);
    attn_kernel<<<BB * NN2 / 16, 256, 0, stream>>>(q1, q2, stats, ctx1, ctx2, rpw, rpb, f2, xbuf);
    mlp_kernel<<<BB * NN2 / 16, 256, 0, stream>>>(xbuf, ln4w, ln4b, ff1w, ff1b, ff2w, ff2b, (float*)d_out);
}

// Round 2
// 352.990 us; speedup vs baseline: 4.3858x; 4.3858x over previous
//
#include <hip/hip_runtime.h>
#include <hip/hip_bf16.h>
#include <math.h>

#define BB 128
#define NN2 1024
#define NN3 256
#define NN4 64
#define DD 128
#define MLPD 512
#define EPSF 1e-5f

typedef short bf16x8 __attribute__((ext_vector_type(8)));
typedef float f32x4 __attribute__((ext_vector_type(4)));

__device__ inline ushort f2b(float x) {
    __hip_bfloat16 h = __float2bfloat16(x);
    return __builtin_bit_cast(ushort, h);
}
__device__ inline float b2f(ushort u) {
    unsigned int v = ((unsigned int)u) << 16;
    return __builtin_bit_cast(float, v);
}

#define MFMA(a, b, c) __builtin_amdgcn_mfma_f32_16x16x32_bf16((a), (b), (c), 0, 0, 0)

// LN of 32 rows (8 threads/row) -> bf16 LDS tile [32][STRIDE]
template <int STRIDE>
__device__ inline void ln_stage(const float* __restrict__ x, long base,
                                const float* __restrict__ w, const float* __restrict__ b,
                                ushort xn[][STRIDE], int t)
{
    int r = t >> 3, l8 = t & 7;
    const float4* xr4 = reinterpret_cast<const float4*>(x + (base + r) * DD);
    float4 v[4];
#pragma unroll
    for (int j = 0; j < 4; ++j) v[j] = xr4[l8 * 4 + j];
    float s = 0.f;
#pragma unroll
    for (int j = 0; j < 4; ++j) s += v[j].x + v[j].y + v[j].z + v[j].w;
#pragma unroll
    for (int m = 1; m <= 4; m <<= 1) s += __shfl_xor(s, m, 64);
    float mean = s * (1.f / 128.f);
    float s2 = 0.f;
#pragma unroll
    for (int j = 0; j < 4; ++j) {
        v[j].x -= mean; v[j].y -= mean; v[j].z -= mean; v[j].w -= mean;
        s2 += v[j].x * v[j].x + v[j].y * v[j].y + v[j].z * v[j].z + v[j].w * v[j].w;
    }
#pragma unroll
    for (int m = 1; m <= 4; m <<= 1) s2 += __shfl_xor(s2, m, 64);
    float rstd = rsqrtf(s2 * (1.f / 128.f) + EPSF);
    int c0 = l8 * 16;
#pragma unroll
    for (int j = 0; j < 4; ++j) {
        int c = c0 + j * 4;
        float o0 = v[j].x * rstd * w[c] + b[c];
        float o1 = v[j].y * rstd * w[c + 1] + b[c + 1];
        float o2 = v[j].z * rstd * w[c + 2] + b[c + 2];
        float o3 = v[j].w * rstd * w[c + 3] + b[c + 3];
        uint2 uu;
        uu.x = (unsigned int)f2b(o0) | ((unsigned int)f2b(o1) << 16);
        uu.y = (unsigned int)f2b(o2) | ((unsigned int)f2b(o3) << 16);
        *reinterpret_cast<uint2*>(&xn[r][c]) = uu;
    }
}

// ---------------- weight convert/transpose to bf16 ------------------------
__global__ __launch_bounds__(256) void prep_w(
    const float* __restrict__ q1w, const float* __restrict__ q2w,
    const float* __restrict__ k1w, const float* __restrict__ v1w,
    const float* __restrict__ k2w, const float* __restrict__ v2w,
    const float* __restrict__ ff1w, const float* __restrict__ ff2w,
    const float* __restrict__ rpw,
    ushort* __restrict__ Wqt, ushort* __restrict__ Wkv3t, ushort* __restrict__ Wkv4t,
    ushort* __restrict__ W1t, ushort* __restrict__ W2t, ushort* __restrict__ RpT)
{
    int tid = blockIdx.x * 256 + threadIdx.x;
    int np = gridDim.x * 256;
    for (int i = tid; i < 256 * 128; i += np) {
        int n = i >> 7, k = i & 127, n2 = n & 127;
        Wqt[i]   = f2b(n < 128 ? q1w[k * 128 + n2] : q2w[k * 128 + n2]);
        Wkv3t[i] = f2b(n < 128 ? k1w[k * 128 + n2] : v1w[k * 128 + n2]);
        Wkv4t[i] = f2b(n < 128 ? k2w[k * 128 + n2] : v2w[k * 128 + n2]);
    }
    for (int i = tid; i < 512 * 128; i += np) {
        int n = i >> 7, k = i & 127;
        W1t[i] = f2b(ff1w[k * 512 + n]);
    }
    for (int i = tid; i < 128 * 512; i += np) {
        int n = i >> 9, k = i & 511;
        W2t[i] = f2b(ff2w[k * 128 + n]);
    }
    for (int i = tid; i < 128 * 256; i += np) {
        int n = i >> 8, k = i & 255;
        RpT[i] = f2b(rpw[k * 128 + n]);
    }
}

// ---------------- pe @ W folds (fp32) -------------------------------------
__global__ __launch_bounds__(256) void prep_pe(
    const float* __restrict__ pe2, const float* __restrict__ pe3, const float* __restrict__ pe4,
    const float* __restrict__ q1w, const float* __restrict__ q1b,
    const float* __restrict__ q2w, const float* __restrict__ q2b,
    const float* __restrict__ k1w, const float* __restrict__ k1b, const float* __restrict__ v1b,
    const float* __restrict__ k2w, const float* __restrict__ k2b, const float* __restrict__ v2b,
    float* __restrict__ peq, float* __restrict__ pekv3, float* __restrict__ pekv4)
{
    int bid = blockIdx.x;
    int c = threadIdx.x;
    int cc = c & 127;
    if (bid < 1024) {
        const float* pr = pe2 + bid * 128;
        const float* w = (c < 128) ? q1w : q2w;
        float acc = (c < 128) ? q1b[cc] : q2b[cc];
        for (int k = 0; k < 128; ++k) acc += pr[k] * w[k * 128 + cc];
        peq[bid * 256 + c] = acc;
    } else if (bid < 1024 + 256) {
        int tok = bid - 1024;
        const float* pr = pe3 + tok * 128;
        float acc;
        if (c < 128) {
            acc = k1b[cc];
            for (int k = 0; k < 128; ++k) acc += pr[k] * k1w[k * 128 + cc];
        } else acc = v1b[cc];
        pekv3[tok * 256 + c] = acc;
    } else {
        int tok = bid - 1280;
        const float* pr = pe4 + tok * 128;
        float acc;
        if (c < 128) {
            acc = k2b[cc];
            for (int k = 0; k < 128; ++k) acc += pr[k] * k2w[k * 128 + cc];
        } else acc = v2b[cc];
        pekv4[tok * 256 + c] = acc;
    }
}

// ---------------- kv path: LN -> MFMA proj -> k channel-softmax -> T store -
__global__ __launch_bounds__(256) void kv_mfma(
    const float* __restrict__ x, const float* __restrict__ lnw, const float* __restrict__ lnb,
    const ushort* __restrict__ Wt, const float* __restrict__ pekv,
    ushort* __restrict__ kst, ushort* __restrict__ vst, int ntok, int ntok_shift)
{
    __shared__ ushort xn[32][136];
    __shared__ ushort trans[4][64][40];
    int t = threadIdx.x;
    long base = (long)blockIdx.x * 32;
    ln_stage<136>(x, base, lnw, lnb, xn, t);
    __syncthreads();
    int w = t >> 6, l = t & 63, l15 = l & 15, rg = l >> 4;
    f32x4 acc[2][4];
#pragma unroll
    for (int m = 0; m < 2; ++m)
#pragma unroll
        for (int n = 0; n < 4; ++n) acc[m][n] = (f32x4){0.f, 0.f, 0.f, 0.f};
#pragma unroll
    for (int kc = 0; kc < 4; ++kc) {
        bf16x8 a0 = *reinterpret_cast<const bf16x8*>(&xn[l15][kc * 32 + rg * 8]);
        bf16x8 a1 = *reinterpret_cast<const bf16x8*>(&xn[16 + l15][kc * 32 + rg * 8]);
#pragma unroll
        for (int nt = 0; nt < 4; ++nt) {
            bf16x8 bfr = *reinterpret_cast<const bf16x8*>(
                &Wt[(size_t)(w * 64 + nt * 16 + l15) * 128 + kc * 32 + rg * 8]);
            acc[0][nt] = MFMA(a0, bfr, acc[0][nt]);
            acc[1][nt] = MFMA(a1, bfr, acc[1][nt]);
        }
    }
    float val[2][4][4];
#pragma unroll
    for (int mt = 0; mt < 2; ++mt)
#pragma unroll
        for (int j = 0; j < 4; ++j) {
            int row = mt * 16 + rg * 4 + j;
            int tok = (int)((base + row) & (ntok - 1));
#pragma unroll
            for (int nt = 0; nt < 4; ++nt) {
                int col = w * 64 + nt * 16 + l15;
                val[mt][nt][j] = acc[mt][nt][j] + pekv[tok * 256 + col];
            }
        }
    if (w < 2) {  // channel softmax within each head (64 cols = this wave)
#pragma unroll
        for (int mt = 0; mt < 2; ++mt)
#pragma unroll
            for (int j = 0; j < 4; ++j) {
                float mx = val[mt][0][j];
#pragma unroll
                for (int nt = 1; nt < 4; ++nt) mx = fmaxf(mx, val[mt][nt][j]);
#pragma unroll
                for (int m = 1; m <= 8; m <<= 1) mx = fmaxf(mx, __shfl_xor(mx, m, 64));
                float e[4], se = 0.f;
#pragma unroll
                for (int nt = 0; nt < 4; ++nt) { e[nt] = __expf(val[mt][nt][j] - mx); se += e[nt]; }
#pragma unroll
                for (int m = 1; m <= 8; m <<= 1) se += __shfl_xor(se, m, 64);
                float inv = 1.f / se;
#pragma unroll
                for (int nt = 0; nt < 4; ++nt) val[mt][nt][j] = e[nt] * inv;
            }
    }
#pragma unroll
    for (int mt = 0; mt < 2; ++mt)
#pragma unroll
        for (int nt = 0; nt < 4; ++nt)
#pragma unroll
            for (int j = 0; j < 4; ++j)
                trans[w][nt * 16 + l15][mt * 16 + rg * 4 + j] = f2b(val[mt][nt][j]);
    __syncthreads();
    ushort* dst = (w < 2) ? kst : vst;
    int h = w & 1;
    int b = (int)(base >> ntok_shift);
    int tok0 = (int)(base & (ntok - 1));
    long o = (((long)(b * 2 + h) * 64 + l) * ntok + tok0);
    const int4* src = reinterpret_cast<const int4*>(&trans[w][l][0]);
    int4* dp = reinterpret_cast<int4*>(&dst[o]);
#pragma unroll
    for (int i = 0; i < 4; ++i) dp[i] = src[i];
}

// ---------------- ctx: [64 d x 64 e] = ks[d][tok] x vs[tok][e] ------------
__global__ __launch_bounds__(64) void ctx_mfma(
    const ushort* __restrict__ kst3, const ushort* __restrict__ vst3,
    const ushort* __restrict__ kst4, const ushort* __restrict__ vst4,
    ushort* __restrict__ ctxt)
{
    __shared__ ushort trans[64][72];
    int bid = blockIdx.x;       // b*4 + g
    int b = bid >> 2, g = bid & 3;
    const ushort* ks; const ushort* vs; int ntok;
    if (g < 2) { ntok = 256; ks = kst3 + (long)(b * 2 + g) * 64 * 256; vs = vst3 + (long)(b * 2 + g) * 64 * 256; }
    else       { ntok = 64;  ks = kst4 + (long)(b * 2 + (g - 2)) * 64 * 64; vs = vst4 + (long)(b * 2 + (g - 2)) * 64 * 64; }
    int l = threadIdx.x, l15 = l & 15, rg = l >> 4;
    f32x4 acc[4][4];
#pragma unroll
    for (int m = 0; m < 4; ++m)
#pragma unroll
        for (int n = 0; n < 4; ++n) acc[m][n] = (f32x4){0.f, 0.f, 0.f, 0.f};
    for (int kc = 0; kc < (ntok >> 5); ++kc) {
        bf16x8 a[4];
#pragma unroll
        for (int mt = 0; mt < 4; ++mt)
            a[mt] = *reinterpret_cast<const bf16x8*>(&ks[(size_t)(mt * 16 + l15) * ntok + kc * 32 + rg * 8]);
#pragma unroll
        for (int nt = 0; nt < 4; ++nt) {
            bf16x8 bfr = *reinterpret_cast<const bf16x8*>(&vs[(size_t)(nt * 16 + l15) * ntok + kc * 32 + rg * 8]);
#pragma unroll
            for (int mt = 0; mt < 4; ++mt) acc[mt][nt] = MFMA(a[mt], bfr, acc[mt][nt]);
        }
    }
#pragma unroll
    for (int mt = 0; mt < 4; ++mt)
#pragma unroll
        for (int nt = 0; nt < 4; ++nt)
#pragma unroll
            for (int j = 0; j < 4; ++j)
                trans[nt * 16 + l15][mt * 16 + rg * 4 + j] = f2b(acc[mt][nt][j]);
    __syncthreads();
    const int4* src = reinterpret_cast<const int4*>(&trans[l][0]);
    int4* dst = reinterpret_cast<int4*>(&ctxt[((long)bid * 64 + l) * 64]);
#pragma unroll
    for (int i = 0; i < 8; ++i) dst[i] = src[i];
}

// ---------------- q path: LN -> MFMA proj -> qcat bf16 + exp partial sums --
__global__ __launch_bounds__(256) void q_mfma(
    const float* __restrict__ f2, const float* __restrict__ lnw, const float* __restrict__ lnb,
    const ushort* __restrict__ Wqt, const float* __restrict__ peq,
    ushort* __restrict__ qcat, float* __restrict__ partial)
{
    __shared__ ushort xn[32][136];
    int t = threadIdx.x;
    long base = (long)blockIdx.x * 32;
    ln_stage<136>(f2, base, lnw, lnb, xn, t);
    __syncthreads();
    int w = t >> 6, l = t & 63, l15 = l & 15, rg = l >> 4;
    f32x4 acc[2][4];
#pragma unroll
    for (int m = 0; m < 2; ++m)
#pragma unroll
        for (int n = 0; n < 4; ++n) acc[m][n] = (f32x4){0.f, 0.f, 0.f, 0.f};
#pragma unroll
    for (int kc = 0; kc < 4; ++kc) {
        bf16x8 a0 = *reinterpret_cast<const bf16x8*>(&xn[l15][kc * 32 + rg * 8]);
        bf16x8 a1 = *reinterpret_cast<const bf16x8*>(&xn[16 + l15][kc * 32 + rg * 8]);
#pragma unroll
        for (int nt = 0; nt < 4; ++nt) {
            bf16x8 bfr = *reinterpret_cast<const bf16x8*>(
                &Wqt[(size_t)(w * 64 + nt * 16 + l15) * 128 + kc * 32 + rg * 8]);
            acc[0][nt] = MFMA(a0, bfr, acc[0][nt]);
            acc[1][nt] = MFMA(a1, bfr, acc[1][nt]);
        }
    }
    float esum[4] = {0.f, 0.f, 0.f, 0.f};
#pragma unroll
    for (int mt = 0; mt < 2; ++mt)
#pragma unroll
        for (int j = 0; j < 4; ++j) {
            int row = mt * 16 + rg * 4 + j;
            int tok = (int)((base + row) & (NN2 - 1));
#pragma unroll
            for (int nt = 0; nt < 4; ++nt) {
                int col = w * 64 + nt * 16 + l15;
                float v = acc[mt][nt][j] + peq[tok * 256 + col];
                qcat[(base + row) * 256 + col] = f2b(v);
                esum[nt] += __expf(v);
            }
        }
#pragma unroll
    for (int nt = 0; nt < 4; ++nt) {
        esum[nt] += __shfl_xor(esum[nt], 16, 64);
        esum[nt] += __shfl_xor(esum[nt], 32, 64);
    }
    if (rg == 0) {
        int bidx = blockIdx.x >> 5, chunk = blockIdx.x & 31;
#pragma unroll
        for (int nt = 0; nt < 4; ++nt)
            partial[(size_t)(bidx * 32 + chunk) * 256 + w * 64 + nt * 16 + l15] = esum[nt];
    }
}

__global__ __launch_bounds__(256) void qsum(const float* __restrict__ partial, float* __restrict__ rs)
{
    int b = blockIdx.x, c = threadIdx.x;
    float s = 0.f;
    for (int ch = 0; ch < 32; ++ch) s += partial[(size_t)(b * 32 + ch) * 256 + c];
    rs[b * 256 + c] = 1.f / s;
}

// ---------------- attn: p=exp(q)*rs -> blockdiag ctx GEMM -> rp GEMM ------
__global__ __launch_bounds__(256) void attn_mfma(
    const ushort* __restrict__ qcat, const float* __restrict__ rs,
    const ushort* __restrict__ ctxt, const ushort* __restrict__ RpT,
    const float* __restrict__ rpb, const float* __restrict__ f2,
    float* __restrict__ xbuf)
{
    __shared__ ushort ps[32][264];
    __shared__ ushort cat[32][264];
    int t = threadIdx.x;
    long base = (long)blockIdx.x * 32;
    int b = blockIdx.x >> 5;
    {
        int r = t >> 3, c0 = (t & 7) * 32;
        const ushort* qr = qcat + (base + r) * 256 + c0;
        const float* rsb = rs + b * 256 + c0;
#pragma unroll
        for (int jj = 0; jj < 4; ++jj) {
            bf16x8 qv = *reinterpret_cast<const bf16x8*>(qr + jj * 8);
            unsigned int outw[4];
#pragma unroll
            for (int p2 = 0; p2 < 4; ++p2) {
                float e0 = __expf(b2f((ushort)qv[p2 * 2]))     * rsb[jj * 8 + p2 * 2];
                float e1 = __expf(b2f((ushort)qv[p2 * 2 + 1])) * rsb[jj * 8 + p2 * 2 + 1];
                outw[p2] = (unsigned int)f2b(e0) | ((unsigned int)f2b(e1) << 16);
            }
            uint4 uu; uu.x = outw[0]; uu.y = outw[1]; uu.z = outw[2]; uu.w = outw[3];
            *reinterpret_cast<uint4*>(&ps[r][c0 + jj * 8]) = uu;
        }
    }
    __syncthreads();
    int w = t >> 6, l = t & 63, l15 = l & 15, rg = l >> 4;
    {
        f32x4 acc[2][4];
#pragma unroll
        for (int m = 0; m < 2; ++m)
#pragma unroll
            for (int n = 0; n < 4; ++n) acc[m][n] = (f32x4){0.f, 0.f, 0.f, 0.f};
        const ushort* cb = ctxt + (long)(b * 4 + w) * 4096;
#pragma unroll
        for (int kc = 0; kc < 2; ++kc) {
            bf16x8 a0 = *reinterpret_cast<const bf16x8*>(&ps[l15][w * 64 + kc * 32 + rg * 8]);
            bf16x8 a1 = *reinterpret_cast<const bf16x8*>(&ps[16 + l15][w * 64 + kc * 32 + rg * 8]);
#pragma unroll
            for (int nt = 0; nt < 4; ++nt) {
                bf16x8 bfr = *reinterpret_cast<const bf16x8*>(&cb[(size_t)(nt * 16 + l15) * 64 + kc * 32 + rg * 8]);
                acc[0][nt] = MFMA(a0, bfr, acc[0][nt]);
                acc[1][nt] = MFMA(a1, bfr, acc[1][nt]);
            }
        }
#pragma unroll
        for (int mt = 0; mt < 2; ++mt)
#pragma unroll
            for (int nt = 0; nt < 4; ++nt)
#pragma unroll
                for (int j = 0; j < 4; ++j)
                    cat[mt * 16 + rg * 4 + j][w * 64 + nt * 16 + l15] = f2b(acc[mt][nt][j]);
    }
    __syncthreads();
    {
        f32x4 acc[2][2];
#pragma unroll
        for (int m = 0; m < 2; ++m)
#pragma unroll
            for (int n = 0; n < 2; ++n) acc[m][n] = (f32x4){0.f, 0.f, 0.f, 0.f};
#pragma unroll
        for (int kc = 0; kc < 8; ++kc) {
            bf16x8 a0 = *reinterpret_cast<const bf16x8*>(&cat[l15][kc * 32 + rg * 8]);
            bf16x8 a1 = *reinterpret_cast<const bf16x8*>(&cat[16 + l15][kc * 32 + rg * 8]);
#pragma unroll
            for (int nt = 0; nt < 2; ++nt) {
                bf16x8 bfr = *reinterpret_cast<const bf16x8*>(
                    &RpT[(size_t)(w * 32 + nt * 16 + l15) * 256 + kc * 32 + rg * 8]);
                acc[0][nt] = MFMA(a0, bfr, acc[0][nt]);
                acc[1][nt] = MFMA(a1, bfr, acc[1][nt]);
            }
        }
#pragma unroll
        for (int mt = 0; mt < 2; ++mt)
#pragma unroll
            for (int nt = 0; nt < 2; ++nt)
#pragma unroll
                for (int j = 0; j < 4; ++j) {
                    int row = mt * 16 + rg * 4 + j;
                    int col = w * 32 + nt * 16 + l15;
                    long g = (base + row) * 128 + col;
                    xbuf[g] = f2[g] + acc[mt][nt][j] + rpb[col];
                }
    }
}

// ---------------- MLP: LN -> GEMM1+gelu -> GEMM2 + residual ---------------
__global__ __launch_bounds__(256) void mlp_mfma(
    const float* __restrict__ x, const float* __restrict__ lnw, const float* __restrict__ lnb,
    const ushort* __restrict__ W1t, const float* __restrict__ ff1b,
    const ushort* __restrict__ W2t, const float* __restrict__ ff2b,
    float* __restrict__ out)
{
    __shared__ ushort xn[32][136];
    __shared__ ushort hid[32][520];
    int t = threadIdx.x;
    long base = (long)blockIdx.x * 32;
    ln_stage<136>(x, base, lnw, lnb, xn, t);
    __syncthreads();
    int w = t >> 6, l = t & 63, l15 = l & 15, rg = l >> 4;
    {
        f32x4 acc[2][8];
#pragma unroll
        for (int m = 0; m < 2; ++m)
#pragma unroll
            for (int n = 0; n < 8; ++n) acc[m][n] = (f32x4){0.f, 0.f, 0.f, 0.f};
#pragma unroll
        for (int kc = 0; kc < 4; ++kc) {
            bf16x8 a0 = *reinterpret_cast<const bf16x8*>(&xn[l15][kc * 32 + rg * 8]);
            bf16x8 a1 = *reinterpret_cast<const bf16x8*>(&xn[16 + l15][kc * 32 + rg * 8]);
#pragma unroll
            for (int nt = 0; nt < 8; ++nt) {
                bf16x8 bfr = *reinterpret_cast<const bf16x8*>(
                    &W1t[(size_t)(w * 128 + nt * 16 + l15) * 128 + kc * 32 + rg * 8]);
                acc[0][nt] = MFMA(a0, bfr, acc[0][nt]);
                acc[1][nt] = MFMA(a1, bfr, acc[1][nt]);
            }
        }
#pragma unroll
        for (int mt = 0; mt < 2; ++mt)
#pragma unroll
            for (int nt = 0; nt < 8; ++nt) {
                int col = w * 128 + nt * 16 + l15;
                float bias = ff1b[col];
#pragma unroll
                for (int j = 0; j < 4; ++j) {
                    float h = acc[mt][nt][j] + bias;
                    float ge = 0.5f * h * (1.f + erff(h * 0.70710678118654752f));
                    hid[mt * 16 + rg * 4 + j][col] = f2b(ge);
                }
            }
    }
    __syncthreads();
    {
        f32x4 acc[2][2];
#pragma unroll
        for (int m = 0; m < 2; ++m)
#pragma unroll
            for (int n = 0; n < 2; ++n) acc[m][n] = (f32x4){0.f, 0.f, 0.f, 0.f};
#pragma unroll
        for (int kc = 0; kc < 16; ++kc) {
            bf16x8 a0 = *reinterpret_cast<const bf16x8*>(&hid[l15][kc * 32 + rg * 8]);
            bf16x8 a1 = *reinterpret_cast<const bf16x8*>(&hid[16 + l15][kc * 32 + rg * 8]);
#pragma unroll
            for (int nt = 0; nt < 2; ++nt) {
                bf16x8 bfr = *reinterpret_cast<const bf16x8*>(
                    &W2t[(size_t)(w * 32 + nt * 16 + l15) * 512 + kc * 32 + rg * 8]);
                acc[0][nt] = MFMA(a0, bfr, acc[0][nt]);
                acc[1][nt] = MFMA(a1, bfr, acc[1][nt]);
            }
        }
#pragma unroll
        for (int mt = 0; mt < 2; ++mt)
#pragma unroll
            for (int nt = 0; nt < 2; ++nt)
#pragma unroll
                for (int j = 0; j < 4; ++j) {
                    int row = mt * 16 + rg * 4 + j;
                    int col = w * 32 + nt * 16 + l15;
                    long g = (base + row) * 128 + col;
                    out[g] = x[g] + acc[mt][nt][j] + ff2b[col];
                }
    }
}

extern "C" void kernel_launch(void* const* d_in, const int* in_sizes, int n_in,
                              void* d_out, int out_size, void* d_ws, size_t ws_size,
                              hipStream_t stream) {
    const float* f2   = (const float*)d_in[0];
    const float* f3   = (const float*)d_in[1];
    const float* f4   = (const float*)d_in[2];
    const float* pe2  = (const float*)d_in[3];
    const float* pe3  = (const float*)d_in[4];
    const float* pe4  = (const float*)d_in[5];
    const float* ln1w = (const float*)d_in[6];
    const float* ln1b = (const float*)d_in[7];
    const float* ln2w = (const float*)d_in[8];
    const float* ln2b = (const float*)d_in[9];
    const float* ln3w = (const float*)d_in[10];
    const float* ln3b = (const float*)d_in[11];
    const float* ln4w = (const float*)d_in[12];
    const float* ln4b = (const float*)d_in[13];
    const float* q1w  = (const float*)d_in[14];
    const float* q1b  = (const float*)d_in[15];
    const float* k1w  = (const float*)d_in[16];
    const float* k1b  = (const float*)d_in[17];
    const float* v1w  = (const float*)d_in[18];
    const float* v1b  = (const float*)d_in[19];
    const float* q2w  = (const float*)d_in[20];
    const float* q2b  = (const float*)d_in[21];
    const float* k2w  = (const float*)d_in[22];
    const float* k2b  = (const float*)d_in[23];
    const float* v2w  = (const float*)d_in[24];
    const float* v2b  = (const float*)d_in[25];
    const float* rpw  = (const float*)d_in[26];
    const float* rpb  = (const float*)d_in[27];
    const float* ff1w = (const float*)d_in[28];
    const float* ff1b = (const float*)d_in[29];
    const float* ff2w = (const float*)d_in[30];
    const float* ff2b = (const float*)d_in[31];

    char* ws = (char*)d_ws;
    size_t off = 0;
    ushort* qcat  = (ushort*)(ws + off); off += (size_t)BB * NN2 * 256 * 2;       // 67MB
    float*  xbuf  = (float*)(ws + off);  off += (size_t)BB * NN2 * DD * 4;        // 67MB
    ushort* kst3  = (ushort*)(ws + off); off += (size_t)BB * 2 * 64 * NN3 * 2;
    ushort* vst3  = (ushort*)(ws + off); off += (size_t)BB * 2 * 64 * NN3 * 2;
    ushort* kst4  = (ushort*)(ws + off); off += (size_t)BB * 2 * 64 * NN4 * 2;
    ushort* vst4  = (ushort*)(ws + off); off += (size_t)BB * 2 * 64 * NN4 * 2;
    ushort* ctxt  = (ushort*)(ws + off); off += (size_t)BB * 4 * 64 * 64 * 2;
    ushort* Wqt   = (ushort*)(ws + off); off += 256 * 128 * 2;
    ushort* Wkv3t = (ushort*)(ws + off); off += 256 * 128 * 2;
    ushort* Wkv4t = (ushort*)(ws + off); off += 256 * 128 * 2;
    ushort* W1t   = (ushort*)(ws + off); off += 512 * 128 * 2;
    ushort* W2t   = (ushort*)(ws + off); off += 128 * 512 * 2;
    ushort* RpT   = (ushort*)(ws + off); off += 128 * 256 * 2;
    float*  peq   = (float*)(ws + off);  off += (size_t)NN2 * 256 * 4;
    float*  pekv3 = (float*)(ws + off);  off += (size_t)NN3 * 256 * 4;
    float*  pekv4 = (float*)(ws + off);  off += (size_t)NN4 * 256 * 4;
    float*  partial = (float*)(ws + off); off += (size_t)BB * 32 * 256 * 4;
    float*  rsbuf = (float*)(ws + off);  off += (size_t)BB * 256 * 4;

    prep_w<<<64, 256, 0, stream>>>(q1w, q2w, k1w, v1w, k2w, v2w, ff1w, ff2w, rpw,
                                   Wqt, Wkv3t, Wkv4t, W1t, W2t, RpT);
    prep_pe<<<1344, 256, 0, stream>>>(pe2, pe3, pe4, q1w, q1b, q2w, q2b,
                                      k1w, k1b, v1b, k2w, k2b, v2b, peq, pekv3, pekv4);
    kv_mfma<<<BB * NN3 / 32, 256, 0, stream>>>(f3, ln2w, ln2b, Wkv3t, pekv3, kst3, vst3, NN3, 8);
    kv_mfma<<<BB * NN4 / 32, 256, 0, stream>>>(f4, ln3w, ln3b, Wkv4t, pekv4, kst4, vst4, NN4, 6);
    ctx_mfma<<<BB * 4, 64, 0, stream>>>(kst3, vst3, kst4, vst4, ctxt);
    q_mfma<<<BB * NN2 / 32, 256, 0, stream>>>(f2, ln1w, ln1b, Wqt, peq, qcat, partial);
    qsum<<<BB, 256, 0, stream>>>(partial, rsbuf);
    attn_mfma<<<BB * NN2 / 32, 256, 0, stream>>>(qcat, rsbuf, ctxt, RpT, rpb, f2, xbuf);
    mlp_mfma<<<BB * NN2 / 32, 256, 0, stream>>>(xbuf, ln4w, ln4b, W1t, ff1b, W2t, ff2b, (float*)d_out);
}

// Round 3
// 315.206 us; speedup vs baseline: 4.9116x; 1.1199x over previous
//
#include <hip/hip_runtime.h>
#include <hip/hip_bf16.h>
#include <math.h>

#define BB 128
#define NN2 1024
#define NN3 256
#define NN4 64
#define DD 128
#define MLPD 512
#define EPSF 1e-5f

typedef short bf16x8 __attribute__((ext_vector_type(8)));
typedef float f32x4 __attribute__((ext_vector_type(4)));

__device__ inline ushort f2b(float x) {
    __hip_bfloat16 h = __float2bfloat16(x);
    return __builtin_bit_cast(ushort, h);
}
__device__ inline float b2f(ushort u) {
    unsigned int v = ((unsigned int)u) << 16;
    return __builtin_bit_cast(float, v);
}
// tanh-form GELU: 0.5x(1+tanh(0.79788456(x+0.044715x^3))) = x*e/(e+1), e=exp(2t)
__device__ inline float gelu_f(float u) {
    float t = 0.7978845608f * u + 0.0356774081f * (u * u * u);
    float e = __expf(2.f * t);
    return u - u / (e + 1.f);
}

#define MFMA(a, b, c) __builtin_amdgcn_mfma_f32_16x16x32_bf16((a), (b), (c), 0, 0, 0)

// LN of 32 rows (8 threads/row) from global -> bf16 LDS tile [32][STRIDE]
template <int STRIDE>
__device__ inline void ln_stage(const float* __restrict__ x, long base,
                                const float* __restrict__ w, const float* __restrict__ b,
                                ushort xn[][STRIDE], int t)
{
    int r = t >> 3, l8 = t & 7;
    const float4* xr4 = reinterpret_cast<const float4*>(x + (base + r) * DD);
    float4 v[4];
#pragma unroll
    for (int j = 0; j < 4; ++j) v[j] = xr4[l8 * 4 + j];
    float s = 0.f;
#pragma unroll
    for (int j = 0; j < 4; ++j) s += v[j].x + v[j].y + v[j].z + v[j].w;
#pragma unroll
    for (int m = 1; m <= 4; m <<= 1) s += __shfl_xor(s, m, 64);
    float mean = s * (1.f / 128.f);
    float s2 = 0.f;
#pragma unroll
    for (int j = 0; j < 4; ++j) {
        v[j].x -= mean; v[j].y -= mean; v[j].z -= mean; v[j].w -= mean;
        s2 += v[j].x * v[j].x + v[j].y * v[j].y + v[j].z * v[j].z + v[j].w * v[j].w;
    }
#pragma unroll
    for (int m = 1; m <= 4; m <<= 1) s2 += __shfl_xor(s2, m, 64);
    float rstd = rsqrtf(s2 * (1.f / 128.f) + EPSF);
    int c0 = l8 * 16;
#pragma unroll
    for (int j = 0; j < 4; ++j) {
        int c = c0 + j * 4;
        float o0 = v[j].x * rstd * w[c] + b[c];
        float o1 = v[j].y * rstd * w[c + 1] + b[c + 1];
        float o2 = v[j].z * rstd * w[c + 2] + b[c + 2];
        float o3 = v[j].w * rstd * w[c + 3] + b[c + 3];
        uint2 uu;
        uu.x = (unsigned int)f2b(o0) | ((unsigned int)f2b(o1) << 16);
        uu.y = (unsigned int)f2b(o2) | ((unsigned int)f2b(o3) << 16);
        *reinterpret_cast<uint2*>(&xn[r][c]) = uu;
    }
}

// ---------------- weight transpose via LDS tiles (coalesced both sides) ----
__global__ __launch_bounds__(256) void prep_tw(
    const float* __restrict__ q1w, const float* __restrict__ q2w,
    const float* __restrict__ k1w, const float* __restrict__ v1w,
    const float* __restrict__ k2w, const float* __restrict__ v2w,
    const float* __restrict__ ff1w, const float* __restrict__ ff2w,
    const float* __restrict__ rpw,
    ushort* __restrict__ Wqt, ushort* __restrict__ Wkv3t, ushort* __restrict__ Wkv4t,
    ushort* __restrict__ W1t, ushort* __restrict__ W2t, ushort* __restrict__ RpT)
{
    __shared__ ushort trans[4][64][88];
    int w = threadIdx.x >> 6, l = threadIdx.x & 63;
    int tile = blockIdx.x * 4 + w;  // 0..63
    const float* src; ushort* dst; int K, N, tk, tn;
    if (tile < 24) {
        int job = tile >> 2, rel = tile & 3;
        K = 128; N = 128; tk = rel >> 1; tn = rel & 1;
        if      (job == 0) { src = q1w; dst = Wqt; }
        else if (job == 1) { src = q2w; dst = Wqt + 16384; }
        else if (job == 2) { src = k1w; dst = Wkv3t; }
        else if (job == 3) { src = v1w; dst = Wkv3t + 16384; }
        else if (job == 4) { src = k2w; dst = Wkv4t; }
        else               { src = v2w; dst = Wkv4t + 16384; }
    } else if (tile < 40) {
        int rel = tile - 24; src = ff1w; dst = W1t; K = 128; N = 512; tk = rel >> 3; tn = rel & 7;
    } else if (tile < 56) {
        int rel = tile - 40; src = ff2w; dst = W2t; K = 512; N = 128; tk = rel >> 1; tn = rel & 1;
    } else {
        int rel = tile - 56; src = rpw; dst = RpT; K = 256; N = 128; tk = rel >> 1; tn = rel & 1;
    }
    int k0 = tk * 64, n0 = tn * 64;
#pragma unroll
    for (int i = 0; i < 16; ++i) {
        int kr = i * 4 + (l >> 4), nc = (l & 15) * 4;
        float4 v = *reinterpret_cast<const float4*>(&src[(size_t)(k0 + kr) * N + n0 + nc]);
        trans[w][nc + 0][kr] = f2b(v.x);
        trans[w][nc + 1][kr] = f2b(v.y);
        trans[w][nc + 2][kr] = f2b(v.z);
        trans[w][nc + 3][kr] = f2b(v.w);
    }
    __syncthreads();
#pragma unroll
    for (int i = 0; i < 8; ++i) {
        int nr = i * 8 + (l >> 3), c0 = (l & 7) * 8;
        int4 vv = *reinterpret_cast<const int4*>(&trans[w][nr][c0]);
        *reinterpret_cast<int4*>(&dst[(size_t)(n0 + nr) * K + k0 + c0]) = vv;
    }
}

// ---------------- pe @ W folds via MFMA ------------------------------------
__global__ __launch_bounds__(256) void prep_pe2(
    const float* __restrict__ pe2, const float* __restrict__ pe3, const float* __restrict__ pe4,
    const ushort* __restrict__ Wqt, const ushort* __restrict__ Wkv3t, const ushort* __restrict__ Wkv4t,
    const float* __restrict__ q1b, const float* __restrict__ q2b,
    const float* __restrict__ k1b, const float* __restrict__ v1b,
    const float* __restrict__ k2b, const float* __restrict__ v2b,
    float* __restrict__ peq, float* __restrict__ pekv3, float* __restrict__ pekv4)
{
    __shared__ ushort xn[32][136];
    int bid = blockIdx.x, t = threadIdx.x;
    const float* pe; const ushort* Wt; float* outp; const float* bl; const float* bh; int hiDot; long tb;
    if (bid < 32)      { pe = pe2; Wt = Wqt;   outp = peq;   bl = q1b; bh = q2b; hiDot = 1; tb = (long)bid * 32; }
    else if (bid < 40) { pe = pe3; Wt = Wkv3t; outp = pekv3; bl = k1b; bh = v1b; hiDot = 0; tb = (long)(bid - 32) * 32; }
    else               { pe = pe4; Wt = Wkv4t; outp = pekv4; bl = k2b; bh = v2b; hiDot = 0; tb = (long)(bid - 40) * 32; }
    {
        int r = t >> 3, l8 = t & 7;
        const float4* pr = reinterpret_cast<const float4*>(pe + (tb + r) * 128);
#pragma unroll
        for (int j = 0; j < 4; ++j) {
            float4 v = pr[l8 * 4 + j];
            int c = l8 * 16 + j * 4;
            uint2 uu;
            uu.x = (unsigned int)f2b(v.x) | ((unsigned int)f2b(v.y) << 16);
            uu.y = (unsigned int)f2b(v.z) | ((unsigned int)f2b(v.w) << 16);
            *reinterpret_cast<uint2*>(&xn[r][c]) = uu;
        }
    }
    __syncthreads();
    int w = t >> 6, l = t & 63, l15 = l & 15, rg = l >> 4;
    f32x4 acc[2][4];
#pragma unroll
    for (int m = 0; m < 2; ++m)
#pragma unroll
        for (int n = 0; n < 4; ++n) acc[m][n] = (f32x4){0.f, 0.f, 0.f, 0.f};
#pragma unroll
    for (int kc = 0; kc < 4; ++kc) {
        bf16x8 a0 = *reinterpret_cast<const bf16x8*>(&xn[l15][kc * 32 + rg * 8]);
        bf16x8 a1 = *reinterpret_cast<const bf16x8*>(&xn[16 + l15][kc * 32 + rg * 8]);
#pragma unroll
        for (int nt = 0; nt < 4; ++nt) {
            bf16x8 bfr = *reinterpret_cast<const bf16x8*>(
                &Wt[(size_t)(w * 64 + nt * 16 + l15) * 128 + kc * 32 + rg * 8]);
            acc[0][nt] = MFMA(a0, bfr, acc[0][nt]);
            acc[1][nt] = MFMA(a1, bfr, acc[1][nt]);
        }
    }
#pragma unroll
    for (int mt = 0; mt < 2; ++mt)
#pragma unroll
        for (int j = 0; j < 4; ++j) {
            int row = mt * 16 + rg * 4 + j;
#pragma unroll
            for (int nt = 0; nt < 4; ++nt) {
                int col = w * 64 + nt * 16 + l15;
                float bias = (col < 128) ? bl[col] : bh[col - 128];
                float v = bias + ((col < 128 || hiDot) ? acc[mt][nt][j] : 0.f);
                outp[(tb + row) * 256 + col] = v;
            }
        }
}

// ---------------- kv path: LN -> MFMA proj -> k channel-softmax -> T store -
__global__ __launch_bounds__(256) void kv_mfma(
    const float* __restrict__ x, const float* __restrict__ lnw, const float* __restrict__ lnb,
    const ushort* __restrict__ Wt, const float* __restrict__ pekv,
    ushort* __restrict__ kst, ushort* __restrict__ vst, int ntok, int ntok_shift)
{
    __shared__ ushort xn[32][136];
    __shared__ ushort trans[4][64][40];
    int t = threadIdx.x;
    long base = (long)blockIdx.x * 32;
    ln_stage<136>(x, base, lnw, lnb, xn, t);
    __syncthreads();
    int w = t >> 6, l = t & 63, l15 = l & 15, rg = l >> 4;
    f32x4 acc[2][4];
#pragma unroll
    for (int m = 0; m < 2; ++m)
#pragma unroll
        for (int n = 0; n < 4; ++n) acc[m][n] = (f32x4){0.f, 0.f, 0.f, 0.f};
#pragma unroll
    for (int kc = 0; kc < 4; ++kc) {
        bf16x8 a0 = *reinterpret_cast<const bf16x8*>(&xn[l15][kc * 32 + rg * 8]);
        bf16x8 a1 = *reinterpret_cast<const bf16x8*>(&xn[16 + l15][kc * 32 + rg * 8]);
#pragma unroll
        for (int nt = 0; nt < 4; ++nt) {
            bf16x8 bfr = *reinterpret_cast<const bf16x8*>(
                &Wt[(size_t)(w * 64 + nt * 16 + l15) * 128 + kc * 32 + rg * 8]);
            acc[0][nt] = MFMA(a0, bfr, acc[0][nt]);
            acc[1][nt] = MFMA(a1, bfr, acc[1][nt]);
        }
    }
    float val[2][4][4];
#pragma unroll
    for (int mt = 0; mt < 2; ++mt)
#pragma unroll
        for (int j = 0; j < 4; ++j) {
            int row = mt * 16 + rg * 4 + j;
            int tok = (int)((base + row) & (ntok - 1));
#pragma unroll
            for (int nt = 0; nt < 4; ++nt) {
                int col = w * 64 + nt * 16 + l15;
                val[mt][nt][j] = acc[mt][nt][j] + pekv[tok * 256 + col];
            }
        }
    if (w < 2) {  // channel softmax within each head (64 cols = this wave)
#pragma unroll
        for (int mt = 0; mt < 2; ++mt)
#pragma unroll
            for (int j = 0; j < 4; ++j) {
                float mx = val[mt][0][j];
#pragma unroll
                for (int nt = 1; nt < 4; ++nt) mx = fmaxf(mx, val[mt][nt][j]);
#pragma unroll
                for (int m = 1; m <= 8; m <<= 1) mx = fmaxf(mx, __shfl_xor(mx, m, 64));
                float e[4], se = 0.f;
#pragma unroll
                for (int nt = 0; nt < 4; ++nt) { e[nt] = __expf(val[mt][nt][j] - mx); se += e[nt]; }
#pragma unroll
                for (int m = 1; m <= 8; m <<= 1) se += __shfl_xor(se, m, 64);
                float inv = 1.f / se;
#pragma unroll
                for (int nt = 0; nt < 4; ++nt) val[mt][nt][j] = e[nt] * inv;
            }
    }
#pragma unroll
    for (int mt = 0; mt < 2; ++mt)
#pragma unroll
        for (int nt = 0; nt < 4; ++nt)
#pragma unroll
            for (int j = 0; j < 4; ++j)
                trans[w][nt * 16 + l15][mt * 16 + rg * 4 + j] = f2b(val[mt][nt][j]);
    __syncthreads();
    ushort* dst = (w < 2) ? kst : vst;
    int h = w & 1;
    int b = (int)(base >> ntok_shift);
    int tok0 = (int)(base & (ntok - 1));
    long o = (((long)(b * 2 + h) * 64 + l) * ntok + tok0);
    const int4* src = reinterpret_cast<const int4*>(&trans[w][l][0]);
    int4* dp = reinterpret_cast<int4*>(&dst[o]);
#pragma unroll
    for (int i = 0; i < 4; ++i) dp[i] = src[i];
}

// ---------------- ctx: [64 d x 64 e] = ks[d][tok] x vs[tok][e] ------------
__global__ __launch_bounds__(64) void ctx_mfma(
    const ushort* __restrict__ kst3, const ushort* __restrict__ vst3,
    const ushort* __restrict__ kst4, const ushort* __restrict__ vst4,
    ushort* __restrict__ ctxt)
{
    __shared__ ushort trans[64][72];
    int bid = blockIdx.x;       // b*4 + g
    int b = bid >> 2, g = bid & 3;
    const ushort* ks; const ushort* vs; int ntok;
    if (g < 2) { ntok = 256; ks = kst3 + (long)(b * 2 + g) * 64 * 256; vs = vst3 + (long)(b * 2 + g) * 64 * 256; }
    else       { ntok = 64;  ks = kst4 + (long)(b * 2 + (g - 2)) * 64 * 64; vs = vst4 + (long)(b * 2 + (g - 2)) * 64 * 64; }
    int l = threadIdx.x, l15 = l & 15, rg = l >> 4;
    f32x4 acc[4][4];
#pragma unroll
    for (int m = 0; m < 4; ++m)
#pragma unroll
        for (int n = 0; n < 4; ++n) acc[m][n] = (f32x4){0.f, 0.f, 0.f, 0.f};
    for (int kc = 0; kc < (ntok >> 5); ++kc) {
        bf16x8 a[4];
#pragma unroll
        for (int mt = 0; mt < 4; ++mt)
            a[mt] = *reinterpret_cast<const bf16x8*>(&ks[(size_t)(mt * 16 + l15) * ntok + kc * 32 + rg * 8]);
#pragma unroll
        for (int nt = 0; nt < 4; ++nt) {
            bf16x8 bfr = *reinterpret_cast<const bf16x8*>(&vs[(size_t)(nt * 16 + l15) * ntok + kc * 32 + rg * 8]);
#pragma unroll
            for (int mt = 0; mt < 4; ++mt) acc[mt][nt] = MFMA(a[mt], bfr, acc[mt][nt]);
        }
    }
#pragma unroll
    for (int mt = 0; mt < 4; ++mt)
#pragma unroll
        for (int nt = 0; nt < 4; ++nt)
#pragma unroll
            for (int j = 0; j < 4; ++j)
                trans[nt * 16 + l15][mt * 16 + rg * 4 + j] = f2b(acc[mt][nt][j]);
    __syncthreads();
    const int4* src = reinterpret_cast<const int4*>(&trans[l][0]);
    int4* dst = reinterpret_cast<int4*>(&ctxt[((long)bid * 64 + l) * 64]);
#pragma unroll
    for (int i = 0; i < 8; ++i) dst[i] = src[i];
}

// ---------------- q path: LN -> MFMA proj -> store exp(q) bf16 + partials --
__global__ __launch_bounds__(256) void q_mfma(
    const float* __restrict__ f2, const float* __restrict__ lnw, const float* __restrict__ lnb,
    const ushort* __restrict__ Wqt, const float* __restrict__ peq,
    ushort* __restrict__ qexp, float* __restrict__ partial)
{
    __shared__ ushort xn[32][136];
    __shared__ ushort qt[32][264];
    int t = threadIdx.x;
    long base = (long)blockIdx.x * 32;
    ln_stage<136>(f2, base, lnw, lnb, xn, t);
    __syncthreads();
    int w = t >> 6, l = t & 63, l15 = l & 15, rg = l >> 4;
    f32x4 acc[2][4];
#pragma unroll
    for (int m = 0; m < 2; ++m)
#pragma unroll
        for (int n = 0; n < 4; ++n) acc[m][n] = (f32x4){0.f, 0.f, 0.f, 0.f};
#pragma unroll
    for (int kc = 0; kc < 4; ++kc) {
        bf16x8 a0 = *reinterpret_cast<const bf16x8*>(&xn[l15][kc * 32 + rg * 8]);
        bf16x8 a1 = *reinterpret_cast<const bf16x8*>(&xn[16 + l15][kc * 32 + rg * 8]);
#pragma unroll
        for (int nt = 0; nt < 4; ++nt) {
            bf16x8 bfr = *reinterpret_cast<const bf16x8*>(
                &Wqt[(size_t)(w * 64 + nt * 16 + l15) * 128 + kc * 32 + rg * 8]);
            acc[0][nt] = MFMA(a0, bfr, acc[0][nt]);
            acc[1][nt] = MFMA(a1, bfr, acc[1][nt]);
        }
    }
    float esum[4] = {0.f, 0.f, 0.f, 0.f};
#pragma unroll
    for (int mt = 0; mt < 2; ++mt)
#pragma unroll
        for (int j = 0; j < 4; ++j) {
            int row = mt * 16 + rg * 4 + j;
            int tok = (int)((base + row) & (NN2 - 1));
#pragma unroll
            for (int nt = 0; nt < 4; ++nt) {
                int col = w * 64 + nt * 16 + l15;
                float v = acc[mt][nt][j] + peq[tok * 256 + col];
                float e = __expf(v);
                qt[row][col] = f2b(e);
                esum[nt] += e;
            }
        }
#pragma unroll
    for (int nt = 0; nt < 4; ++nt) {
        esum[nt] += __shfl_xor(esum[nt], 16, 64);
        esum[nt] += __shfl_xor(esum[nt], 32, 64);
    }
    if (rg == 0) {
        int bidx = blockIdx.x >> 5, chunk = blockIdx.x & 31;
#pragma unroll
        for (int nt = 0; nt < 4; ++nt)
            partial[(size_t)(bidx * 32 + chunk) * 256 + w * 64 + nt * 16 + l15] = esum[nt];
    }
    __syncthreads();
    {
        int r = t >> 3, c0 = (t & 7) * 32;
        const int4* sp = reinterpret_cast<const int4*>(&qt[r][c0]);
        int4* dst = reinterpret_cast<int4*>(&qexp[(base + r) * 256 + c0]);
#pragma unroll
        for (int i = 0; i < 4; ++i) dst[i] = sp[i];
    }
}

// ---------------- reduce partials -> fold 1/sum into ctx ------------------
__global__ __launch_bounds__(256) void qsum_scale(
    const float* __restrict__ partial, ushort* __restrict__ ctxt)
{
    int b = blockIdx.x, c = threadIdx.x;
    float s = 0.f;
    for (int ch = 0; ch < 32; ++ch) s += partial[((size_t)b * 32 + ch) * 256 + c];
    float rsv = 1.f / s;
    ushort* row = ctxt + (((long)b * 4 + (c >> 6)) * 64 + (c & 63)) * 64;
#pragma unroll
    for (int i = 0; i < 8; ++i) {
        int4 vv = *reinterpret_cast<int4*>(&row[i * 8]);
        ushort* u = reinterpret_cast<ushort*>(&vv);
#pragma unroll
        for (int j = 0; j < 8; ++j) u[j] = f2b(b2f(u[j]) * rsv);
        *reinterpret_cast<int4*>(&row[i * 8]) = vv;
    }
}

// ---------------- fused: blockdiag ctx GEMM -> rp -> LN -> MLP -> out ------
__global__ __launch_bounds__(256) void attn_mlp(
    const ushort* __restrict__ qexp, const ushort* __restrict__ ctxt,
    const ushort* __restrict__ RpT, const float* __restrict__ rpb,
    const float* __restrict__ f2,
    const float* __restrict__ lnw, const float* __restrict__ lnb,
    const ushort* __restrict__ W1t, const float* __restrict__ ff1b,
    const ushort* __restrict__ W2t, const float* __restrict__ ff2b,
    float* __restrict__ out)
{
    __shared__ __align__(16) char smem[42496];
    float  (*xf)[132]  = reinterpret_cast<float (*)[132]>(smem);            // R0 16896B
    ushort (*cat)[264] = reinterpret_cast<ushort (*)[264]>(smem + 16896);   // R1 16896B
    ushort (*xn)[136]  = reinterpret_cast<ushort (*)[136]>(smem + 33792);   // R2 8704B
    ushort (*hid)[520] = reinterpret_cast<ushort (*)[520]>(smem);           // R0+R1 33280B
    int t = threadIdx.x;
    long base = (long)blockIdx.x * 32;
    int b = blockIdx.x >> 5;
    int w = t >> 6, l = t & 63, l15 = l & 15, rg = l >> 4;

    // Phase B: blockdiag P @ ctx' (A-frags straight from global qexp)
    {
        f32x4 acc[2][4];
#pragma unroll
        for (int m = 0; m < 2; ++m)
#pragma unroll
            for (int n = 0; n < 4; ++n) acc[m][n] = (f32x4){0.f, 0.f, 0.f, 0.f};
        const ushort* cb = ctxt + ((long)b * 4 + w) * 4096;
#pragma unroll
        for (int kc = 0; kc < 2; ++kc) {
            bf16x8 a0 = *reinterpret_cast<const bf16x8*>(&qexp[(base + l15) * 256 + w * 64 + kc * 32 + rg * 8]);
            bf16x8 a1 = *reinterpret_cast<const bf16x8*>(&qexp[(base + 16 + l15) * 256 + w * 64 + kc * 32 + rg * 8]);
#pragma unroll
            for (int nt = 0; nt < 4; ++nt) {
                bf16x8 bfr = *reinterpret_cast<const bf16x8*>(&cb[(size_t)(nt * 16 + l15) * 64 + kc * 32 + rg * 8]);
                acc[0][nt] = MFMA(a0, bfr, acc[0][nt]);
                acc[1][nt] = MFMA(a1, bfr, acc[1][nt]);
            }
        }
#pragma unroll
        for (int mt = 0; mt < 2; ++mt)
#pragma unroll
            for (int nt = 0; nt < 4; ++nt)
#pragma unroll
                for (int j = 0; j < 4; ++j)
                    cat[mt * 16 + rg * 4 + j][w * 64 + nt * 16 + l15] = f2b(acc[mt][nt][j]);
    }
    __syncthreads();
    float xres[2][2][4];
    // Phase C: rp GEMM + residual -> xres regs + xf LDS
    {
        f32x4 acc[2][2];
#pragma unroll
        for (int m = 0; m < 2; ++m)
#pragma unroll
            for (int n = 0; n < 2; ++n) acc[m][n] = (f32x4){0.f, 0.f, 0.f, 0.f};
#pragma unroll
        for (int kc = 0; kc < 8; ++kc) {
            bf16x8 a0 = *reinterpret_cast<const bf16x8*>(&cat[l15][kc * 32 + rg * 8]);
            bf16x8 a1 = *reinterpret_cast<const bf16x8*>(&cat[16 + l15][kc * 32 + rg * 8]);
#pragma unroll
            for (int nt = 0; nt < 2; ++nt) {
                bf16x8 bfr = *reinterpret_cast<const bf16x8*>(
                    &RpT[(size_t)(w * 32 + nt * 16 + l15) * 256 + kc * 32 + rg * 8]);
                acc[0][nt] = MFMA(a0, bfr, acc[0][nt]);
                acc[1][nt] = MFMA(a1, bfr, acc[1][nt]);
            }
        }
#pragma unroll
        for (int mt = 0; mt < 2; ++mt)
#pragma unroll
            for (int nt = 0; nt < 2; ++nt)
#pragma unroll
                for (int j = 0; j < 4; ++j) {
                    int row = mt * 16 + rg * 4 + j;
                    int col = w * 32 + nt * 16 + l15;
                    long g = (base + row) * 128 + col;
                    float xv = f2[g] + acc[mt][nt][j] + rpb[col];
                    xres[mt][nt][j] = xv;
                    xf[row][col] = xv;
                }
    }
    __syncthreads();
    // Phase D: LN from xf -> xn
    {
        int r = t >> 3, l8 = t & 7;
        float4 v[4];
#pragma unroll
        for (int j = 0; j < 4; ++j) v[j] = *reinterpret_cast<float4*>(&xf[r][l8 * 16 + 4 * j]);
        float s = 0.f;
#pragma unroll
        for (int j = 0; j < 4; ++j) s += v[j].x + v[j].y + v[j].z + v[j].w;
#pragma unroll
        for (int m = 1; m <= 4; m <<= 1) s += __shfl_xor(s, m, 64);
        float mean = s * (1.f / 128.f);
        float s2 = 0.f;
#pragma unroll
        for (int j = 0; j < 4; ++j) {
            v[j].x -= mean; v[j].y -= mean; v[j].z -= mean; v[j].w -= mean;
            s2 += v[j].x * v[j].x + v[j].y * v[j].y + v[j].z * v[j].z + v[j].w * v[j].w;
        }
#pragma unroll
        for (int m = 1; m <= 4; m <<= 1) s2 += __shfl_xor(s2, m, 64);
        float rstd = rsqrtf(s2 * (1.f / 128.f) + EPSF);
        int c0 = l8 * 16;
#pragma unroll
        for (int j = 0; j < 4; ++j) {
            int c = c0 + j * 4;
            float o0 = v[j].x * rstd * lnw[c] + lnb[c];
            float o1 = v[j].y * rstd * lnw[c + 1] + lnb[c + 1];
            float o2 = v[j].z * rstd * lnw[c + 2] + lnb[c + 2];
            float o3 = v[j].w * rstd * lnw[c + 3] + lnb[c + 3];
            uint2 uu;
            uu.x = (unsigned int)f2b(o0) | ((unsigned int)f2b(o1) << 16);
            uu.y = (unsigned int)f2b(o2) | ((unsigned int)f2b(o3) << 16);
            *reinterpret_cast<uint2*>(&xn[r][c]) = uu;
        }
    }
    __syncthreads();
    // Phase E: GEMM1 + fast gelu -> hid (aliases xf/cat; both dead)
    {
        f32x4 acc[2][8];
#pragma unroll
        for (int m = 0; m < 2; ++m)
#pragma unroll
            for (int n = 0; n < 8; ++n) acc[m][n] = (f32x4){0.f, 0.f, 0.f, 0.f};
#pragma unroll
        for (int kc = 0; kc < 4; ++kc) {
            bf16x8 a0 = *reinterpret_cast<const bf16x8*>(&xn[l15][kc * 32 + rg * 8]);
            bf16x8 a1 = *reinterpret_cast<const bf16x8*>(&xn[16 + l15][kc * 32 + rg * 8]);
#pragma unroll
            for (int nt = 0; nt < 8; ++nt) {
                bf16x8 bfr = *reinterpret_cast<const bf16x8*>(
                    &W1t[(size_t)(w * 128 + nt * 16 + l15) * 128 + kc * 32 + rg * 8]);
                acc[0][nt] = MFMA(a0, bfr, acc[0][nt]);
                acc[1][nt] = MFMA(a1, bfr, acc[1][nt]);
            }
        }
#pragma unroll
        for (int mt = 0; mt < 2; ++mt)
#pragma unroll
            for (int nt = 0; nt < 8; ++nt) {
                int col = w * 128 + nt * 16 + l15;
                float bias = ff1b[col];
#pragma unroll
                for (int j = 0; j < 4; ++j) {
                    float h = acc[mt][nt][j] + bias;
                    hid[mt * 16 + rg * 4 + j][col] = f2b(gelu_f(h));
                }
            }
    }
    __syncthreads();
    // Phase F: GEMM2 + residual from regs -> out
    {
        f32x4 acc[2][2];
#pragma unroll
        for (int m = 0; m < 2; ++m)
#pragma unroll
            for (int n = 0; n < 2; ++n) acc[m][n] = (f32x4){0.f, 0.f, 0.f, 0.f};
#pragma unroll
        for (int kc = 0; kc < 16; ++kc) {
            bf16x8 a0 = *reinterpret_cast<const bf16x8*>(&hid[l15][kc * 32 + rg * 8]);
            bf16x8 a1 = *reinterpret_cast<const bf16x8*>(&hid[16 + l15][kc * 32 + rg * 8]);
#pragma unroll
            for (int nt = 0; nt < 2; ++nt) {
                bf16x8 bfr = *reinterpret_cast<const bf16x8*>(
                    &W2t[(size_t)(w * 32 + nt * 16 + l15) * 512 + kc * 32 + rg * 8]);
                acc[0][nt] = MFMA(a0, bfr, acc[0][nt]);
                acc[1][nt] = MFMA(a1, bfr, acc[1][nt]);
            }
        }
#pragma unroll
        for (int mt = 0; mt < 2; ++mt)
#pragma unroll
            for (int nt = 0; nt < 2; ++nt)
#pragma unroll
                for (int j = 0; j < 4; ++j) {
                    int row = mt * 16 + rg * 4 + j;
                    int col = w * 32 + nt * 16 + l15;
                    long g = (base + row) * 128 + col;
                    out[g] = xres[mt][nt][j] + acc[mt][nt][j] + ff2b[col];
                }
    }
}

extern "C" void kernel_launch(void* const* d_in, const int* in_sizes, int n_in,
                              void* d_out, int out_size, void* d_ws, size_t ws_size,
                              hipStream_t stream) {
    const float* f2   = (const float*)d_in[0];
    const float* f3   = (const float*)d_in[1];
    const float* f4   = (const float*)d_in[2];
    const float* pe2  = (const float*)d_in[3];
    const float* pe3  = (const float*)d_in[4];
    const float* pe4  = (const float*)d_in[5];
    const float* ln1w = (const float*)d_in[6];
    const float* ln1b = (const float*)d_in[7];
    const float* ln2w = (const float*)d_in[8];
    const float* ln2b = (const float*)d_in[9];
    const float* ln3w = (const float*)d_in[10];
    const float* ln3b = (const float*)d_in[11];
    const float* ln4w = (const float*)d_in[12];
    const float* ln4b = (const float*)d_in[13];
    const float* q1w  = (const float*)d_in[14];
    const float* q1b  = (const float*)d_in[15];
    const float* k1w  = (const float*)d_in[16];
    const float* k1b  = (const float*)d_in[17];
    const float* v1w  = (const float*)d_in[18];
    const float* v1b  = (const float*)d_in[19];
    const float* q2w  = (const float*)d_in[20];
    const float* q2b  = (const float*)d_in[21];
    const float* k2w  = (const float*)d_in[22];
    const float* k2b  = (const float*)d_in[23];
    const float* v2w  = (const float*)d_in[24];
    const float* v2b  = (const float*)d_in[25];
    const float* rpw  = (const float*)d_in[26];
    const float* rpb  = (const float*)d_in[27];
    const float* ff1w = (const float*)d_in[28];
    const float* ff1b = (const float*)d_in[29];
    const float* ff2w = (const float*)d_in[30];
    const float* ff2b = (const float*)d_in[31];

    char* ws = (char*)d_ws;
    size_t off = 0;
    ushort* qexp  = (ushort*)(ws + off); off += (size_t)BB * NN2 * 256 * 2;
    ushort* kst3  = (ushort*)(ws + off); off += (size_t)BB * 2 * 64 * NN3 * 2;
    ushort* vst3  = (ushort*)(ws + off); off += (size_t)BB * 2 * 64 * NN3 * 2;
    ushort* kst4  = (ushort*)(ws + off); off += (size_t)BB * 2 * 64 * NN4 * 2;
    ushort* vst4  = (ushort*)(ws + off); off += (size_t)BB * 2 * 64 * NN4 * 2;
    ushort* ctxt  = (ushort*)(ws + off); off += (size_t)BB * 4 * 64 * 64 * 2;
    ushort* Wqt   = (ushort*)(ws + off); off += 256 * 128 * 2;
    ushort* Wkv3t = (ushort*)(ws + off); off += 256 * 128 * 2;
    ushort* Wkv4t = (ushort*)(ws + off); off += 256 * 128 * 2;
    ushort* W1t   = (ushort*)(ws + off); off += 512 * 128 * 2;
    ushort* W2t   = (ushort*)(ws + off); off += 128 * 512 * 2;
    ushort* RpT   = (ushort*)(ws + off); off += 128 * 256 * 2;
    float*  peq   = (float*)(ws + off);  off += (size_t)NN2 * 256 * 4;
    float*  pekv3 = (float*)(ws + off);  off += (size_t)NN3 * 256 * 4;
    float*  pekv4 = (float*)(ws + off);  off += (size_t)NN4 * 256 * 4;
    float*  partial = (float*)(ws + off); off += (size_t)BB * 32 * 256 * 4;

    prep_tw<<<16, 256, 0, stream>>>(q1w, q2w, k1w, v1w, k2w, v2w, ff1w, ff2w, rpw,
                                    Wqt, Wkv3t, Wkv4t, W1t, W2t, RpT);
    prep_pe2<<<42, 256, 0, stream>>>(pe2, pe3, pe4, Wqt, Wkv3t, Wkv4t,
                                     q1b, q2b, k1b, v1b, k2b, v2b, peq, pekv3, pekv4);
    kv_mfma<<<BB * NN3 / 32, 256, 0, stream>>>(f3, ln2w, ln2b, Wkv3t, pekv3, kst3, vst3, NN3, 8);
    kv_mfma<<<BB * NN4 / 32, 256, 0, stream>>>(f4, ln3w, ln3b, Wkv4t, pekv4, kst4, vst4, NN4, 6);
    ctx_mfma<<<BB * 4, 64, 0, stream>>>(kst3, vst3, kst4, vst4, ctxt);
    q_mfma<<<BB * NN2 / 32, 256, 0, stream>>>(f2, ln1w, ln1b, Wqt, peq, qexp, partial);
    qsum_scale<<<BB, 256, 0, stream>>>(partial, ctxt);
    attn_mlp<<<BB * NN2 / 32, 256, 0, stream>>>(qexp, ctxt, RpT, rpb, f2,
                                                ln4w, ln4b, W1t, ff1b, W2t, ff2b, (float*)d_out);
}

// Round 4
// 278.451 us; speedup vs baseline: 5.5599x; 1.1320x over previous
//
#include <hip/hip_runtime.h>
#include <hip/hip_bf16.h>
#include <math.h>

#define BB 128
#define NN2 1024
#define NN3 256
#define NN4 64
#define DD 128
#define MLPD 512
#define EPSF 1e-5f

typedef short bf16x8 __attribute__((ext_vector_type(8)));
typedef float f32x4 __attribute__((ext_vector_type(4)));

__device__ inline ushort f2b(float x) {
    __hip_bfloat16 h = __float2bfloat16(x);
    return __builtin_bit_cast(ushort, h);
}
__device__ inline float b2f(ushort u) {
    unsigned int v = ((unsigned int)u) << 16;
    return __builtin_bit_cast(float, v);
}
// tanh-form GELU via exp
__device__ inline float gelu_f(float u) {
    float t = 0.7978845608f * u + 0.0356774081f * (u * u * u);
    float e = __expf(2.f * t);
    return u - u / (e + 1.f);
}

#define MFMA(a, b, c) __builtin_amdgcn_mfma_f32_16x16x32_bf16((a), (b), (c), 0, 0, 0)

// LN of 32 rows (8 threads/row) from global -> bf16 LDS tile [32][STRIDE]
template <int STRIDE>
__device__ inline void ln_stage(const float* __restrict__ x, long base,
                                const float* __restrict__ w, const float* __restrict__ b,
                                ushort xn[][STRIDE], int t)
{
    int r = t >> 3, l8 = t & 7;
    const float4* xr4 = reinterpret_cast<const float4*>(x + (base + r) * DD);
    float4 v[4];
#pragma unroll
    for (int j = 0; j < 4; ++j) v[j] = xr4[l8 * 4 + j];
    float s = 0.f;
#pragma unroll
    for (int j = 0; j < 4; ++j) s += v[j].x + v[j].y + v[j].z + v[j].w;
#pragma unroll
    for (int m = 1; m <= 4; m <<= 1) s += __shfl_xor(s, m, 64);
    float mean = s * (1.f / 128.f);
    float s2 = 0.f;
#pragma unroll
    for (int j = 0; j < 4; ++j) {
        v[j].x -= mean; v[j].y -= mean; v[j].z -= mean; v[j].w -= mean;
        s2 += v[j].x * v[j].x + v[j].y * v[j].y + v[j].z * v[j].z + v[j].w * v[j].w;
    }
#pragma unroll
    for (int m = 1; m <= 4; m <<= 1) s2 += __shfl_xor(s2, m, 64);
    float rstd = rsqrtf(s2 * (1.f / 128.f) + EPSF);
    int c0 = l8 * 16;
#pragma unroll
    for (int j = 0; j < 4; ++j) {
        int c = c0 + j * 4;
        float o0 = v[j].x * rstd * w[c] + b[c];
        float o1 = v[j].y * rstd * w[c + 1] + b[c + 1];
        float o2 = v[j].z * rstd * w[c + 2] + b[c + 2];
        float o3 = v[j].w * rstd * w[c + 3] + b[c + 3];
        uint2 uu;
        uu.x = (unsigned int)f2b(o0) | ((unsigned int)f2b(o1) << 16);
        uu.y = (unsigned int)f2b(o2) | ((unsigned int)f2b(o3) << 16);
        *reinterpret_cast<uint2*>(&xn[r][c]) = uu;
    }
}

// ---------------- weight transpose via LDS tiles (coalesced both sides) ----
__global__ __launch_bounds__(256) void prep_tw(
    const float* __restrict__ q1w, const float* __restrict__ q2w,
    const float* __restrict__ k1w, const float* __restrict__ v1w,
    const float* __restrict__ k2w, const float* __restrict__ v2w,
    const float* __restrict__ ff1w, const float* __restrict__ ff2w,
    const float* __restrict__ rpw,
    ushort* __restrict__ Wqt, ushort* __restrict__ Wkv3t, ushort* __restrict__ Wkv4t,
    ushort* __restrict__ W1t, ushort* __restrict__ W2t, ushort* __restrict__ RpT)
{
    __shared__ ushort trans[4][64][88];
    int w = threadIdx.x >> 6, l = threadIdx.x & 63;
    int tile = blockIdx.x * 4 + w;  // 0..63
    const float* src; ushort* dst; int K, N, tk, tn;
    if (tile < 24) {
        int job = tile >> 2, rel = tile & 3;
        K = 128; N = 128; tk = rel >> 1; tn = rel & 1;
        if      (job == 0) { src = q1w; dst = Wqt; }
        else if (job == 1) { src = q2w; dst = Wqt + 16384; }
        else if (job == 2) { src = k1w; dst = Wkv3t; }
        else if (job == 3) { src = v1w; dst = Wkv3t + 16384; }
        else if (job == 4) { src = k2w; dst = Wkv4t; }
        else               { src = v2w; dst = Wkv4t + 16384; }
    } else if (tile < 40) {
        int rel = tile - 24; src = ff1w; dst = W1t; K = 128; N = 512; tk = rel >> 3; tn = rel & 7;
    } else if (tile < 56) {
        int rel = tile - 40; src = ff2w; dst = W2t; K = 512; N = 128; tk = rel >> 1; tn = rel & 1;
    } else {
        int rel = tile - 56; src = rpw; dst = RpT; K = 256; N = 128; tk = rel >> 1; tn = rel & 1;
    }
    int k0 = tk * 64, n0 = tn * 64;
#pragma unroll
    for (int i = 0; i < 16; ++i) {
        int kr = i * 4 + (l >> 4), nc = (l & 15) * 4;
        float4 v = *reinterpret_cast<const float4*>(&src[(size_t)(k0 + kr) * N + n0 + nc]);
        trans[w][nc + 0][kr] = f2b(v.x);
        trans[w][nc + 1][kr] = f2b(v.y);
        trans[w][nc + 2][kr] = f2b(v.z);
        trans[w][nc + 3][kr] = f2b(v.w);
    }
    __syncthreads();
#pragma unroll
    for (int i = 0; i < 8; ++i) {
        int nr = i * 8 + (l >> 3), c0 = (l & 7) * 8;
        int4 vv = *reinterpret_cast<const int4*>(&trans[w][nr][c0]);
        *reinterpret_cast<int4*>(&dst[(size_t)(n0 + nr) * K + k0 + c0]) = vv;
    }
}

// ---------------- pe @ W folds via MFMA ------------------------------------
__global__ __launch_bounds__(256) void prep_pe2(
    const float* __restrict__ pe2, const float* __restrict__ pe3, const float* __restrict__ pe4,
    const ushort* __restrict__ Wqt, const ushort* __restrict__ Wkv3t, const ushort* __restrict__ Wkv4t,
    const float* __restrict__ q1b, const float* __restrict__ q2b,
    const float* __restrict__ k1b, const float* __restrict__ v1b,
    const float* __restrict__ k2b, const float* __restrict__ v2b,
    float* __restrict__ peq, float* __restrict__ pekv3, float* __restrict__ pekv4)
{
    __shared__ ushort xn[32][136];
    int bid = blockIdx.x, t = threadIdx.x;
    const float* pe; const ushort* Wt; float* outp; const float* bl; const float* bh; int hiDot; long tb;
    if (bid < 32)      { pe = pe2; Wt = Wqt;   outp = peq;   bl = q1b; bh = q2b; hiDot = 1; tb = (long)bid * 32; }
    else if (bid < 40) { pe = pe3; Wt = Wkv3t; outp = pekv3; bl = k1b; bh = v1b; hiDot = 0; tb = (long)(bid - 32) * 32; }
    else               { pe = pe4; Wt = Wkv4t; outp = pekv4; bl = k2b; bh = v2b; hiDot = 0; tb = (long)(bid - 40) * 32; }
    {
        int r = t >> 3, l8 = t & 7;
        const float4* pr = reinterpret_cast<const float4*>(pe + (tb + r) * 128);
#pragma unroll
        for (int j = 0; j < 4; ++j) {
            float4 v = pr[l8 * 4 + j];
            int c = l8 * 16 + j * 4;
            uint2 uu;
            uu.x = (unsigned int)f2b(v.x) | ((unsigned int)f2b(v.y) << 16);
            uu.y = (unsigned int)f2b(v.z) | ((unsigned int)f2b(v.w) << 16);
            *reinterpret_cast<uint2*>(&xn[r][c]) = uu;
        }
    }
    __syncthreads();
    int w = t >> 6, l = t & 63, l15 = l & 15, rg = l >> 4;
    f32x4 acc[2][4];
#pragma unroll
    for (int m = 0; m < 2; ++m)
#pragma unroll
        for (int n = 0; n < 4; ++n) acc[m][n] = (f32x4){0.f, 0.f, 0.f, 0.f};
#pragma unroll
    for (int kc = 0; kc < 4; ++kc) {
        bf16x8 a0 = *reinterpret_cast<const bf16x8*>(&xn[l15][kc * 32 + rg * 8]);
        bf16x8 a1 = *reinterpret_cast<const bf16x8*>(&xn[16 + l15][kc * 32 + rg * 8]);
#pragma unroll
        for (int nt = 0; nt < 4; ++nt) {
            bf16x8 bfr = *reinterpret_cast<const bf16x8*>(
                &Wt[(size_t)(w * 64 + nt * 16 + l15) * 128 + kc * 32 + rg * 8]);
            acc[0][nt] = MFMA(a0, bfr, acc[0][nt]);
            acc[1][nt] = MFMA(a1, bfr, acc[1][nt]);
        }
    }
#pragma unroll
    for (int mt = 0; mt < 2; ++mt)
#pragma unroll
        for (int j = 0; j < 4; ++j) {
            int row = mt * 16 + rg * 4 + j;
#pragma unroll
            for (int nt = 0; nt < 4; ++nt) {
                int col = w * 64 + nt * 16 + l15;
                float bias = (col < 128) ? bl[col] : bh[col - 128];
                float v = bias + ((col < 128 || hiDot) ? acc[mt][nt][j] : 0.f);
                outp[(tb + row) * 256 + col] = v;
            }
        }
}

// ---------------- kv path: LN -> MFMA proj -> k channel-softmax -> T store -
__global__ __launch_bounds__(256) void kv_mfma(
    const float* __restrict__ x, const float* __restrict__ lnw, const float* __restrict__ lnb,
    const ushort* __restrict__ Wt, const float* __restrict__ pekv,
    ushort* __restrict__ kst, ushort* __restrict__ vst, int ntok, int ntok_shift)
{
    __shared__ ushort xn[32][136];
    __shared__ ushort trans[4][64][40];
    int t = threadIdx.x;
    long base = (long)blockIdx.x * 32;
    ln_stage<136>(x, base, lnw, lnb, xn, t);
    __syncthreads();
    int w = t >> 6, l = t & 63, l15 = l & 15, rg = l >> 4;
    f32x4 acc[2][4];
#pragma unroll
    for (int m = 0; m < 2; ++m)
#pragma unroll
        for (int n = 0; n < 4; ++n) acc[m][n] = (f32x4){0.f, 0.f, 0.f, 0.f};
#pragma unroll
    for (int kc = 0; kc < 4; ++kc) {
        bf16x8 a0 = *reinterpret_cast<const bf16x8*>(&xn[l15][kc * 32 + rg * 8]);
        bf16x8 a1 = *reinterpret_cast<const bf16x8*>(&xn[16 + l15][kc * 32 + rg * 8]);
#pragma unroll
        for (int nt = 0; nt < 4; ++nt) {
            bf16x8 bfr = *reinterpret_cast<const bf16x8*>(
                &Wt[(size_t)(w * 64 + nt * 16 + l15) * 128 + kc * 32 + rg * 8]);
            acc[0][nt] = MFMA(a0, bfr, acc[0][nt]);
            acc[1][nt] = MFMA(a1, bfr, acc[1][nt]);
        }
    }
    float val[2][4][4];
#pragma unroll
    for (int mt = 0; mt < 2; ++mt)
#pragma unroll
        for (int j = 0; j < 4; ++j) {
            int row = mt * 16 + rg * 4 + j;
            int tok = (int)((base + row) & (ntok - 1));
#pragma unroll
            for (int nt = 0; nt < 4; ++nt) {
                int col = w * 64 + nt * 16 + l15;
                val[mt][nt][j] = acc[mt][nt][j] + pekv[tok * 256 + col];
            }
        }
    if (w < 2) {  // channel softmax within each head (64 cols = this wave)
#pragma unroll
        for (int mt = 0; mt < 2; ++mt)
#pragma unroll
            for (int j = 0; j < 4; ++j) {
                float mx = val[mt][0][j];
#pragma unroll
                for (int nt = 1; nt < 4; ++nt) mx = fmaxf(mx, val[mt][nt][j]);
#pragma unroll
                for (int m = 1; m <= 8; m <<= 1) mx = fmaxf(mx, __shfl_xor(mx, m, 64));
                float e[4], se = 0.f;
#pragma unroll
                for (int nt = 0; nt < 4; ++nt) { e[nt] = __expf(val[mt][nt][j] - mx); se += e[nt]; }
#pragma unroll
                for (int m = 1; m <= 8; m <<= 1) se += __shfl_xor(se, m, 64);
                float inv = 1.f / se;
#pragma unroll
                for (int nt = 0; nt < 4; ++nt) val[mt][nt][j] = e[nt] * inv;
            }
    }
#pragma unroll
    for (int mt = 0; mt < 2; ++mt)
#pragma unroll
        for (int nt = 0; nt < 4; ++nt)
#pragma unroll
            for (int j = 0; j < 4; ++j)
                trans[w][nt * 16 + l15][mt * 16 + rg * 4 + j] = f2b(val[mt][nt][j]);
    __syncthreads();
    ushort* dst = (w < 2) ? kst : vst;
    int h = w & 1;
    int b = (int)(base >> ntok_shift);
    int tok0 = (int)(base & (ntok - 1));
    long o = (((long)(b * 2 + h) * 64 + l) * ntok + tok0);
    const int4* src = reinterpret_cast<const int4*>(&trans[w][l][0]);
    int4* dp = reinterpret_cast<int4*>(&dst[o]);
#pragma unroll
    for (int i = 0; i < 4; ++i) dp[i] = src[i];
}

// ---------------- ctx: [64 d x 64 e] = ks[d][tok] x vs[tok][e] ------------
__global__ __launch_bounds__(64) void ctx_mfma(
    const ushort* __restrict__ kst3, const ushort* __restrict__ vst3,
    const ushort* __restrict__ kst4, const ushort* __restrict__ vst4,
    ushort* __restrict__ ctxt)
{
    __shared__ ushort trans[64][72];
    int bid = blockIdx.x;       // b*4 + g
    int b = bid >> 2, g = bid & 3;
    const ushort* ks; const ushort* vs; int ntok;
    if (g < 2) { ntok = 256; ks = kst3 + (long)(b * 2 + g) * 64 * 256; vs = vst3 + (long)(b * 2 + g) * 64 * 256; }
    else       { ntok = 64;  ks = kst4 + (long)(b * 2 + (g - 2)) * 64 * 64; vs = vst4 + (long)(b * 2 + (g - 2)) * 64 * 64; }
    int l = threadIdx.x, l15 = l & 15, rg = l >> 4;
    f32x4 acc[4][4];
#pragma unroll
    for (int m = 0; m < 4; ++m)
#pragma unroll
        for (int n = 0; n < 4; ++n) acc[m][n] = (f32x4){0.f, 0.f, 0.f, 0.f};
    for (int kc = 0; kc < (ntok >> 5); ++kc) {
        bf16x8 a[4];
#pragma unroll
        for (int mt = 0; mt < 4; ++mt)
            a[mt] = *reinterpret_cast<const bf16x8*>(&ks[(size_t)(mt * 16 + l15) * ntok + kc * 32 + rg * 8]);
#pragma unroll
        for (int nt = 0; nt < 4; ++nt) {
            bf16x8 bfr = *reinterpret_cast<const bf16x8*>(&vs[(size_t)(nt * 16 + l15) * ntok + kc * 32 + rg * 8]);
#pragma unroll
            for (int mt = 0; mt < 4; ++mt) acc[mt][nt] = MFMA(a[mt], bfr, acc[mt][nt]);
        }
    }
#pragma unroll
    for (int mt = 0; mt < 4; ++mt)
#pragma unroll
        for (int nt = 0; nt < 4; ++nt)
#pragma unroll
            for (int j = 0; j < 4; ++j)
                trans[nt * 16 + l15][mt * 16 + rg * 4 + j] = f2b(acc[mt][nt][j]);
    __syncthreads();
    const int4* src = reinterpret_cast<const int4*>(&trans[l][0]);
    int4* dst = reinterpret_cast<int4*>(&ctxt[((long)bid * 64 + l) * 64]);
#pragma unroll
    for (int i = 0; i < 8; ++i) dst[i] = src[i];
}

// ---------------- q path (64 rows, 512 thr): LN -> proj -> exp(q) + partials
__global__ __launch_bounds__(512) void q_mfma(
    const float* __restrict__ f2, const float* __restrict__ lnw, const float* __restrict__ lnb,
    const ushort* __restrict__ Wqt, const float* __restrict__ peq,
    ushort* __restrict__ qexp, float* __restrict__ partial)
{
    __shared__ ushort xn[64][136];
    __shared__ ushort qt[64][264];
    int t = threadIdx.x;
    long base = (long)blockIdx.x * 64;
    {
        int r = t >> 3, l8 = t & 7;
        const float4* xr4 = reinterpret_cast<const float4*>(f2 + (base + r) * DD);
        float4 v[4];
#pragma unroll
        for (int j = 0; j < 4; ++j) v[j] = xr4[l8 * 4 + j];
        float s = 0.f;
#pragma unroll
        for (int j = 0; j < 4; ++j) s += v[j].x + v[j].y + v[j].z + v[j].w;
#pragma unroll
        for (int m = 1; m <= 4; m <<= 1) s += __shfl_xor(s, m, 64);
        float mean = s * (1.f / 128.f);
        float s2 = 0.f;
#pragma unroll
        for (int j = 0; j < 4; ++j) {
            v[j].x -= mean; v[j].y -= mean; v[j].z -= mean; v[j].w -= mean;
            s2 += v[j].x * v[j].x + v[j].y * v[j].y + v[j].z * v[j].z + v[j].w * v[j].w;
        }
#pragma unroll
        for (int m = 1; m <= 4; m <<= 1) s2 += __shfl_xor(s2, m, 64);
        float rstd = rsqrtf(s2 * (1.f / 128.f) + EPSF);
        int c0 = l8 * 16;
#pragma unroll
        for (int j = 0; j < 4; ++j) {
            int c = c0 + j * 4;
            float o0 = v[j].x * rstd * lnw[c] + lnb[c];
            float o1 = v[j].y * rstd * lnw[c + 1] + lnb[c + 1];
            float o2 = v[j].z * rstd * lnw[c + 2] + lnb[c + 2];
            float o3 = v[j].w * rstd * lnw[c + 3] + lnb[c + 3];
            uint2 uu;
            uu.x = (unsigned int)f2b(o0) | ((unsigned int)f2b(o1) << 16);
            uu.y = (unsigned int)f2b(o2) | ((unsigned int)f2b(o3) << 16);
            *reinterpret_cast<uint2*>(&xn[r][c]) = uu;
        }
    }
    __syncthreads();
    int w = t >> 6, l = t & 63, l15 = l & 15, rg = l >> 4;
    f32x4 acc[4][2];
#pragma unroll
    for (int m = 0; m < 4; ++m)
#pragma unroll
        for (int n = 0; n < 2; ++n) acc[m][n] = (f32x4){0.f, 0.f, 0.f, 0.f};
#pragma unroll
    for (int kc = 0; kc < 4; ++kc) {
        bf16x8 a[4];
#pragma unroll
        for (int m = 0; m < 4; ++m)
            a[m] = *reinterpret_cast<const bf16x8*>(&xn[m * 16 + l15][kc * 32 + rg * 8]);
#pragma unroll
        for (int nt = 0; nt < 2; ++nt) {
            bf16x8 bfr = *reinterpret_cast<const bf16x8*>(
                &Wqt[(size_t)(w * 32 + nt * 16 + l15) * 128 + kc * 32 + rg * 8]);
#pragma unroll
            for (int m = 0; m < 4; ++m) acc[m][nt] = MFMA(a[m], bfr, acc[m][nt]);
        }
    }
    float esum[2] = {0.f, 0.f};
#pragma unroll
    for (int m = 0; m < 4; ++m)
#pragma unroll
        for (int j = 0; j < 4; ++j) {
            int row = m * 16 + rg * 4 + j;
            int tok = (int)((base + row) & (NN2 - 1));
#pragma unroll
            for (int nt = 0; nt < 2; ++nt) {
                int col = w * 32 + nt * 16 + l15;
                float v = acc[m][nt][j] + peq[tok * 256 + col];
                float e = __expf(v);
                qt[row][col] = f2b(e);
                esum[nt] += e;
            }
        }
#pragma unroll
    for (int nt = 0; nt < 2; ++nt) {
        esum[nt] += __shfl_xor(esum[nt], 16, 64);
        esum[nt] += __shfl_xor(esum[nt], 32, 64);
    }
    if (rg == 0) {
        int bidx = blockIdx.x >> 4, chunk = blockIdx.x & 15;
#pragma unroll
        for (int nt = 0; nt < 2; ++nt)
            partial[(size_t)(bidx * 16 + chunk) * 256 + w * 32 + nt * 16 + l15] = esum[nt];
    }
    __syncthreads();
    {
        int r = t >> 3, c0 = (t & 7) * 32;
        const int4* sp = reinterpret_cast<const int4*>(&qt[r][c0]);
        int4* dst = reinterpret_cast<int4*>(&qexp[(base + r) * 256 + c0]);
#pragma unroll
        for (int i = 0; i < 4; ++i) dst[i] = sp[i];
    }
}

// ---------------- reduce partials -> fold 1/sum into ctx ------------------
__global__ __launch_bounds__(256) void qsum_scale(
    const float* __restrict__ partial, ushort* __restrict__ ctxt)
{
    int b = blockIdx.x, c = threadIdx.x;
    float s = 0.f;
    for (int ch = 0; ch < 16; ++ch) s += partial[((size_t)b * 16 + ch) * 256 + c];
    float rsv = 1.f / s;
    ushort* row = ctxt + (((long)b * 4 + (c >> 6)) * 64 + (c & 63)) * 64;
#pragma unroll
    for (int i = 0; i < 8; ++i) {
        int4 vv = *reinterpret_cast<int4*>(&row[i * 8]);
        ushort* u = reinterpret_cast<ushort*>(&vv);
#pragma unroll
        for (int j = 0; j < 8; ++j) u[j] = f2b(b2f(u[j]) * rsv);
        *reinterpret_cast<int4*>(&row[i * 8]) = vv;
    }
}

// ------- fused (64 rows, 512 thr): attn GEMM -> rp -> LN -> MLP -> out -----
__global__ __launch_bounds__(512, 4) void attn_mlp(
    const ushort* __restrict__ qexp, const ushort* __restrict__ ctxt,
    const ushort* __restrict__ RpT, const float* __restrict__ rpb,
    const float* __restrict__ f2,
    const float* __restrict__ lnw, const float* __restrict__ lnb,
    const ushort* __restrict__ W1t, const float* __restrict__ ff1b,
    const ushort* __restrict__ W2t, const float* __restrict__ ff2b,
    float* __restrict__ out)
{
    __shared__ __align__(16) char smem[68608];
    ushort (*xbf)[136]  = reinterpret_cast<ushort (*)[136]>(smem);           // 17408B
    ushort (*work)[264] = reinterpret_cast<ushort (*)[264]>(smem + 17408);   // 33792B (cat / hid-half)
    ushort (*xn)[136]   = reinterpret_cast<ushort (*)[136]>(smem + 51200);   // 17408B
    int t = threadIdx.x;
    long base = (long)blockIdx.x * 64;
    int b = blockIdx.x >> 4;
    int w = t >> 6, l = t & 63, l15 = l & 15, rg = l >> 4;

    // Phase B: blockdiag exp(q) @ ctx' -> cat (work)
    {
        int g = w >> 1, sub = (w & 1) * 32;
        const ushort* cb = ctxt + ((long)b * 4 + g) * 4096;
        bf16x8 bfrB[2][2];
#pragma unroll
        for (int kc = 0; kc < 2; ++kc)
#pragma unroll
            for (int nt = 0; nt < 2; ++nt)
                bfrB[kc][nt] = *reinterpret_cast<const bf16x8*>(
                    &cb[(size_t)(sub + nt * 16 + l15) * 64 + kc * 32 + rg * 8]);
        f32x4 acc[4][2];
#pragma unroll
        for (int m = 0; m < 4; ++m)
#pragma unroll
            for (int n = 0; n < 2; ++n) acc[m][n] = (f32x4){0.f, 0.f, 0.f, 0.f};
#pragma unroll
        for (int m = 0; m < 4; ++m)
#pragma unroll
            for (int kc = 0; kc < 2; ++kc) {
                bf16x8 a = *reinterpret_cast<const bf16x8*>(
                    &qexp[(base + m * 16 + l15) * 256 + g * 64 + kc * 32 + rg * 8]);
#pragma unroll
                for (int nt = 0; nt < 2; ++nt) acc[m][nt] = MFMA(a, bfrB[kc][nt], acc[m][nt]);
            }
#pragma unroll
        for (int m = 0; m < 4; ++m)
#pragma unroll
            for (int nt = 0; nt < 2; ++nt)
#pragma unroll
                for (int j = 0; j < 4; ++j)
                    work[m * 16 + rg * 4 + j][w * 32 + nt * 16 + l15] = f2b(acc[m][nt][j]);
    }
    __syncthreads();
    float xres[4][4];
    // Phase C: rp GEMM (K=256) + residual -> xres regs + xbf LDS
    {
        f32x4 acc[4];
#pragma unroll
        for (int m = 0; m < 4; ++m) acc[m] = (f32x4){0.f, 0.f, 0.f, 0.f};
#pragma unroll
        for (int kc = 0; kc < 8; ++kc) {
            bf16x8 bfr = *reinterpret_cast<const bf16x8*>(
                &RpT[(size_t)(w * 16 + l15) * 256 + kc * 32 + rg * 8]);
#pragma unroll
            for (int m = 0; m < 4; ++m) {
                bf16x8 a = *reinterpret_cast<const bf16x8*>(&work[m * 16 + l15][kc * 32 + rg * 8]);
                acc[m] = MFMA(a, bfr, acc[m]);
            }
        }
        int col = w * 16 + l15;
        float bias = rpb[col];
#pragma unroll
        for (int m = 0; m < 4; ++m)
#pragma unroll
            for (int j = 0; j < 4; ++j) {
                int row = m * 16 + rg * 4 + j;
                long g = (base + row) * 128 + col;
                float xv = f2[g] + acc[m][j] + bias;
                xres[m][j] = xv;
                xbf[row][col] = f2b(xv);
            }
    }
    __syncthreads();
    // Phase D: LN(x) -> xn
    {
        int r = t >> 3, l8 = t & 7;
        bf16x8 r0 = *reinterpret_cast<const bf16x8*>(&xbf[r][l8 * 16]);
        bf16x8 r1 = *reinterpret_cast<const bf16x8*>(&xbf[r][l8 * 16 + 8]);
        float v[16];
#pragma unroll
        for (int i = 0; i < 8; ++i) { v[i] = b2f((ushort)r0[i]); v[8 + i] = b2f((ushort)r1[i]); }
        float s = 0.f;
#pragma unroll
        for (int i = 0; i < 16; ++i) s += v[i];
#pragma unroll
        for (int m = 1; m <= 4; m <<= 1) s += __shfl_xor(s, m, 64);
        float mean = s * (1.f / 128.f);
        float s2 = 0.f;
#pragma unroll
        for (int i = 0; i < 16; ++i) { v[i] -= mean; s2 += v[i] * v[i]; }
#pragma unroll
        for (int m = 1; m <= 4; m <<= 1) s2 += __shfl_xor(s2, m, 64);
        float rstd = rsqrtf(s2 * (1.f / 128.f) + EPSF);
        unsigned int uu[8];
#pragma unroll
        for (int p = 0; p < 8; ++p) {
            int c = l8 * 16 + p * 2;
            float o0 = v[p * 2] * rstd * lnw[c] + lnb[c];
            float o1 = v[p * 2 + 1] * rstd * lnw[c + 1] + lnb[c + 1];
            uu[p] = (unsigned int)f2b(o0) | ((unsigned int)f2b(o1) << 16);
        }
        uint4 w0; w0.x = uu[0]; w0.y = uu[1]; w0.z = uu[2]; w0.w = uu[3];
        uint4 w1; w1.x = uu[4]; w1.y = uu[5]; w1.z = uu[6]; w1.w = uu[7];
        *reinterpret_cast<uint4*>(&xn[r][l8 * 16]) = w0;
        *reinterpret_cast<uint4*>(&xn[r][l8 * 16 + 8]) = w1;
    }
    __syncthreads();
    f32x4 accF[4];
#pragma unroll
    for (int m = 0; m < 4; ++m) accF[m] = (f32x4){0.f, 0.f, 0.f, 0.f};
#pragma unroll
    for (int half = 0; half < 2; ++half) {
        // Phase E: GEMM1 half (256 cols) + gelu -> work
        {
            f32x4 acc[4][2];
#pragma unroll
            for (int m = 0; m < 4; ++m)
#pragma unroll
                for (int n = 0; n < 2; ++n) acc[m][n] = (f32x4){0.f, 0.f, 0.f, 0.f};
#pragma unroll
            for (int kc = 0; kc < 4; ++kc) {
                bf16x8 a[4];
#pragma unroll
                for (int m = 0; m < 4; ++m)
                    a[m] = *reinterpret_cast<const bf16x8*>(&xn[m * 16 + l15][kc * 32 + rg * 8]);
#pragma unroll
                for (int nt = 0; nt < 2; ++nt) {
                    bf16x8 bfr = *reinterpret_cast<const bf16x8*>(
                        &W1t[(size_t)(half * 256 + w * 32 + nt * 16 + l15) * 128 + kc * 32 + rg * 8]);
#pragma unroll
                    for (int m = 0; m < 4; ++m) acc[m][nt] = MFMA(a[m], bfr, acc[m][nt]);
                }
            }
#pragma unroll
            for (int nt = 0; nt < 2; ++nt) {
                int lc = w * 32 + nt * 16 + l15;
                float bias = ff1b[half * 256 + lc];
#pragma unroll
                for (int m = 0; m < 4; ++m)
#pragma unroll
                    for (int j = 0; j < 4; ++j)
                        work[m * 16 + rg * 4 + j][lc] = f2b(gelu_f(acc[m][nt][j] + bias));
            }
        }
        __syncthreads();
        // Phase F: GEMM2 accumulate (K-half = 256)
        {
#pragma unroll
            for (int kc = 0; kc < 8; ++kc) {
                bf16x8 bfr = *reinterpret_cast<const bf16x8*>(
                    &W2t[(size_t)(w * 16 + l15) * 512 + half * 256 + kc * 32 + rg * 8]);
#pragma unroll
                for (int m = 0; m < 4; ++m) {
                    bf16x8 a = *reinterpret_cast<const bf16x8*>(&work[m * 16 + l15][kc * 32 + rg * 8]);
                    accF[m] = MFMA(a, bfr, accF[m]);
                }
            }
        }
        if (half == 0) __syncthreads();
    }
    // epilogue: out = x + mlp + b2
    {
        int col = w * 16 + l15;
        float bias = ff2b[col];
#pragma unroll
        for (int m = 0; m < 4; ++m)
#pragma unroll
            for (int j = 0; j < 4; ++j) {
                int row = m * 16 + rg * 4 + j;
                long g = (base + row) * 128 + col;
                out[g] = xres[m][j] + accF[m][j] + bias;
            }
    }
}

extern "C" void kernel_launch(void* const* d_in, const int* in_sizes, int n_in,
                              void* d_out, int out_size, void* d_ws, size_t ws_size,
                              hipStream_t stream) {
    const float* f2   = (const float*)d_in[0];
    const float* f3   = (const float*)d_in[1];
    const float* f4   = (const float*)d_in[2];
    const float* pe2  = (const float*)d_in[3];
    const float* pe3  = (const float*)d_in[4];
    const float* pe4  = (const float*)d_in[5];
    const float* ln1w = (const float*)d_in[6];
    const float* ln1b = (const float*)d_in[7];
    const float* ln2w = (const float*)d_in[8];
    const float* ln2b = (const float*)d_in[9];
    const float* ln3w = (const float*)d_in[10];
    const float* ln3b = (const float*)d_in[11];
    const float* ln4w = (const float*)d_in[12];
    const float* ln4b = (const float*)d_in[13];
    const float* q1w  = (const float*)d_in[14];
    const float* q1b  = (const float*)d_in[15];
    const float* k1w  = (const float*)d_in[16];
    const float* k1b  = (const float*)d_in[17];
    const float* v1w  = (const float*)d_in[18];
    const float* v1b  = (const float*)d_in[19];
    const float* q2w  = (const float*)d_in[20];
    const float* q2b  = (const float*)d_in[21];
    const float* k2w  = (const float*)d_in[22];
    const float* k2b  = (const float*)d_in[23];
    const float* v2w  = (const float*)d_in[24];
    const float* v2b  = (const float*)d_in[25];
    const float* rpw  = (const float*)d_in[26];
    const float* rpb  = (const float*)d_in[27];
    const float* ff1w = (const float*)d_in[28];
    const float* ff1b = (const float*)d_in[29];
    const float* ff2w = (const float*)d_in[30];
    const float* ff2b = (const float*)d_in[31];

    char* ws = (char*)d_ws;
    size_t off = 0;
    ushort* qexp  = (ushort*)(ws + off); off += (size_t)BB * NN2 * 256 * 2;
    ushort* kst3  = (ushort*)(ws + off); off += (size_t)BB * 2 * 64 * NN3 * 2;
    ushort* vst3  = (ushort*)(ws + off); off += (size_t)BB * 2 * 64 * NN3 * 2;
    ushort* kst4  = (ushort*)(ws + off); off += (size_t)BB * 2 * 64 * NN4 * 2;
    ushort* vst4  = (ushort*)(ws + off); off += (size_t)BB * 2 * 64 * NN4 * 2;
    ushort* ctxt  = (ushort*)(ws + off); off += (size_t)BB * 4 * 64 * 64 * 2;
    ushort* Wqt   = (ushort*)(ws + off); off += 256 * 128 * 2;
    ushort* Wkv3t = (ushort*)(ws + off); off += 256 * 128 * 2;
    ushort* Wkv4t = (ushort*)(ws + off); off += 256 * 128 * 2;
    ushort* W1t   = (ushort*)(ws + off); off += 512 * 128 * 2;
    ushort* W2t   = (ushort*)(ws + off); off += 128 * 512 * 2;
    ushort* RpT   = (ushort*)(ws + off); off += 128 * 256 * 2;
    float*  peq   = (float*)(ws + off);  off += (size_t)NN2 * 256 * 4;
    float*  pekv3 = (float*)(ws + off);  off += (size_t)NN3 * 256 * 4;
    float*  pekv4 = (float*)(ws + off);  off += (size_t)NN4 * 256 * 4;
    float*  partial = (float*)(ws + off); off += (size_t)BB * 16 * 256 * 4;

    prep_tw<<<16, 256, 0, stream>>>(q1w, q2w, k1w, v1w, k2w, v2w, ff1w, ff2w, rpw,
                                    Wqt, Wkv3t, Wkv4t, W1t, W2t, RpT);
    prep_pe2<<<42, 256, 0, stream>>>(pe2, pe3, pe4, Wqt, Wkv3t, Wkv4t,
                                     q1b, q2b, k1b, v1b, k2b, v2b, peq, pekv3, pekv4);
    kv_mfma<<<BB * NN3 / 32, 256, 0, stream>>>(f3, ln2w, ln2b, Wkv3t, pekv3, kst3, vst3, NN3, 8);
    kv_mfma<<<BB * NN4 / 32, 256, 0, stream>>>(f4, ln3w, ln3b, Wkv4t, pekv4, kst4, vst4, NN4, 6);
    ctx_mfma<<<BB * 4, 64, 0, stream>>>(kst3, vst3, kst4, vst4, ctxt);
    q_mfma<<<BB * NN2 / 64, 512, 0, stream>>>(f2, ln1w, ln1b, Wqt, peq, qexp, partial);
    qsum_scale<<<BB, 256, 0, stream>>>(partial, ctxt);
    attn_mlp<<<BB * NN2 / 64, 512, 0, stream>>>(qexp, ctxt, RpT, rpb, f2,
                                                ln4w, ln4b, W1t, ff1b, W2t, ff2b, (float*)d_out);
}